// Round 17
// baseline (1323.104 us; speedup 1.0000x reference)
//
#include <hip/hip_runtime.h>
#include <hip/hip_bf16.h>
#include <math.h>

#define EPS 1e-5f

typedef short bfrag8 __attribute__((ext_vector_type(8)));   // 8 bf16 (4 VGPRs)
typedef float f32x4 __attribute__((ext_vector_type(4)));
typedef unsigned short ushort_t;

__device__ inline ushort_t f2bf(float f) {
    __hip_bfloat16 h = __float2bfloat16(f);
    return *reinterpret_cast<ushort_t*>(&h);
}
__device__ inline float bf2f(ushort_t u) {
    unsigned int v = ((unsigned int)u) << 16;
    float f;
    __builtin_memcpy(&f, &v, 4);
    return f;
}

// ====== weight prepack: fp32 [M][R] -> bf16 [Mpad][Rpad] (zero-padded) ======
__global__ __launch_bounds__(256) void pack_w_kernel(
    const float* __restrict__ src, ushort_t* __restrict__ dst,
    int M, int R, int Mpad, int Rpad)
{
    const int idx = blockIdx.x * 256 + threadIdx.x;
    if (idx >= Mpad * Rpad) return;
    const int m = idx / Rpad, r = idx % Rpad;
    float v = 0.0f;
    if (m < M && r < R) v = src[(size_t)m * R + r];
    dst[idx] = f2bf(v);
}

// ================= fused modulated-deformable-conv stage (MFMA) =============
// One block (256 thr = 4 waves) per TILE consecutive output pixels (one row,
// NT = TILE/16 MFMA n-tiles, LRLIM = min(TILE,16)).
// PMODE 0: global im2col + global bilinear                     (dcn4)
// PMODE 2: fp32 halo patch, phase0b + LDS phase2 bilinear     (dcn1)
// PMODE 3: bf16 halo patch, phase0b + LDS phase2 bilinear     (dcn2, dcn3)
// Halo = 1 px; samples outside the patch fall back to exact global path.
// s_u is a UNION: im2col operand for phase1, then cols for phase3; the
// __syncthreads at each boundary implies lgkmcnt(0) -> race-free.
// r16: phase 0b processes rr-QUADS: 4 patch reads + pack -> 1 ds_write_b64
// (XOR swizzle touches only bits>=3, rr0%4==0 -> quad stays contiguous).
template<int CIN, int COUT, int K, int STRIDE, int PAD, int TILE, int PMODE>
__global__ __launch_bounds__(256, 4) void dcn_mfma_kernel(
    const float* __restrict__ x, int H, int W,
    const ushort_t* __restrict__ wpk,   // [COUT][Rpad] bf16
    const float* __restrict__ bias,     // [COUT]
    const ushort_t* __restrict__ owpk,  // [M1pad][Rpad] bf16
    const float* __restrict__ ob,       // [3P]
    float* __restrict__ out, int Ho, int Wo)
{
    constexpr int P     = K * K;
    constexpr int P3    = 3 * P;
    constexpr int R     = CIN * P;
    constexpr int Rpad  = (R + 63) & ~63;
    constexpr int KT    = Rpad / 32;
    constexpr int NT    = (TILE + 15) / 16;   // MFMA n-tiles
    constexpr int MT1   = (P3 + 15) / 16;     // m-tiles, offset conv
    constexpr int MT1PW = (MT1 + 3) / 4;
    constexpr int MT3   = COUT / 16;          // m-tiles, main conv
    constexpr int MT3PW = (MT3 + 3) / 4;
    constexpr int COLS  = (TILE - 1) * STRIDE + K;
    constexpr int PROWS = K + 2;              // halo rows (modes 2/3)
    constexpr int PCOLS = COLS + 2;           // halo cols (modes 2/3)
    constexpr int PELN  = CIN * PROWS * PCOLS;
    // raw patch buffer in 32-bit units (fp32 for PMODE2, bf16 for PMODE3)
    constexpr int P32   = (PMODE == 2) ? PELN : (PMODE == 3) ? (PELN + 1) / 2 : 1;
    constexpr int LRLIM = (TILE < 16) ? TILE : 16;

    __shared__ unsigned int s_patch32[P32];
    __shared__ ushort_t s_u[TILE * Rpad];     // union: pc (ph0b/1), cols (ph2/3)
    __shared__ float s_py[TILE][P];
    __shared__ float s_px[TILE][P];
    __shared__ ushort_t s_mask[TILE][P];      // bf16

    ushort_t* s_patchh = (ushort_t*)s_patch32;
    float*    s_patchf = (float*)s_patch32;

    const int tilesPerImg = (Ho * Wo) / TILE;
    const int b    = blockIdx.x / tilesPerImg;
    const int tile = blockIdx.x % tilesPerImg;
    const int base = tile * TILE;             // TILE | Wo -> single output row
    const int tid  = threadIdx.x;
    const int wid  = tid >> 6, lane = tid & 63;
    const int lr   = lane & 15;               // fragment row / pixel column
    const int lk8  = (lane >> 4) * 8;         // fragment K offset (elements)

    const int oy0 = base / Wo;
    const int ox0 = base % Wo;
    const int iy0 = oy0 * STRIDE - PAD;
    const int ix0 = ox0 * STRIDE - PAD;

    const float* xb = x + (size_t)b * CIN * H * W;

    // ---- phase 0a: halo patch -> LDS ----
    if constexpr (PMODE == 2 || PMODE == 3) {
        for (int idx = tid; idx < PELN; idx += 256) {
            const int c   = idx / (PROWS * PCOLS);
            const int rem = idx % (PROWS * PCOLS);
            const int pr  = rem / PCOLS;
            const int pc_ = rem % PCOLS;
            const int iy = iy0 - 1 + pr, ix = ix0 - 1 + pc_;
            float v = 0.0f;
            if (iy >= 0 && iy < H && ix >= 0 && ix < W)
                v = xb[(size_t)c * H * W + iy * W + ix];
            if constexpr (PMODE == 2) s_patchf[idx] = v;
            else                      s_patchh[idx] = f2bf(v);
        }
        __syncthreads();
    }

    // ---- phase 0b: im2col expand -> s_u ----
    if constexpr (PMODE == 2 || PMODE == 3) {
        // quad path: 4 consecutive rr -> one ds_write_b64
        constexpr int QUADS = Rpad / 4;
        for (int rq = tid; rq < QUADS; rq += 256) {
            const int rr0 = rq * 4;
            int off[4];
            #pragma unroll
            for (int e = 0; e < 4; ++e) {
                const int rr = rr0 + e;
                if (rr < R) {
                    const int c = rr / P, p = rr % P;
                    const int ky = p / K, kx = p % K;
                    off[e] = (c * PROWS + ky + 1) * PCOLS + kx + 1;
                } else {
                    off[e] = -1;
                }
            }
            #pragma unroll 4
            for (int pix = 0; pix < TILE; ++pix) {
                const int sh = pix * STRIDE;
                ushort_t h0, h1, h2, h3;
                if constexpr (PMODE == 2) {
                    h0 = off[0] >= 0 ? f2bf(s_patchf[off[0] + sh]) : (ushort_t)0;
                    h1 = off[1] >= 0 ? f2bf(s_patchf[off[1] + sh]) : (ushort_t)0;
                    h2 = off[2] >= 0 ? f2bf(s_patchf[off[2] + sh]) : (ushort_t)0;
                    h3 = off[3] >= 0 ? f2bf(s_patchf[off[3] + sh]) : (ushort_t)0;
                } else {
                    h0 = off[0] >= 0 ? s_patchh[off[0] + sh] : (ushort_t)0;
                    h1 = off[1] >= 0 ? s_patchh[off[1] + sh] : (ushort_t)0;
                    h2 = off[2] >= 0 ? s_patchh[off[2] + sh] : (ushort_t)0;
                    h3 = off[3] >= 0 ? s_patchh[off[3] + sh] : (ushort_t)0;
                }
                const unsigned int lo = (unsigned int)h0 | ((unsigned int)h1 << 16);
                const unsigned int hi = (unsigned int)h2 | ((unsigned int)h3 << 16);
                const unsigned long long w =
                    (unsigned long long)lo | ((unsigned long long)hi << 32);
                *(unsigned long long*)&s_u[pix * Rpad +
                    (rr0 ^ ((pix & 7) << 3))] = w;
            }
        }
    } else {
        for (int rr = tid; rr < Rpad; rr += 256) {
            if (rr < R) {
                const int c = rr / P, p = rr % P;
                const int ky = p / K, kx = p % K;
                const int iy = iy0 + ky;
                const bool rowok = (iy >= 0 && iy < H);
                const float* xrow = xb + (size_t)c * H * W +
                                    (size_t)(rowok ? iy : 0) * W;
                #pragma unroll 4
                for (int pix = 0; pix < TILE; ++pix) {
                    const int ix = ix0 + pix * STRIDE + kx;
                    float v = 0.0f;
                    if (rowok && ix >= 0 && ix < W) v = xrow[ix];
                    s_u[pix * Rpad + (rr ^ ((pix & 7) << 3))] = f2bf(v);
                }
            } else {
                #pragma unroll 4
                for (int pix = 0; pix < TILE; ++pix)
                    s_u[pix * Rpad + (rr ^ ((pix & 7) << 3))] = 0;
            }
        }
    }
    __syncthreads();

    // ---- phase 1: offset conv via MFMA; fused-coord epilogue ----
    {
        f32x4 acc1[MT1PW][NT] = {};
        for (int kt = 0; kt < KT; ++kt) {
            bfrag8 bfr[NT];
            #pragma unroll
            for (int nt = 0; nt < NT; ++nt)
                bfr[nt] = *(const bfrag8*)&s_u[(nt * 16 + lr) * Rpad +
                              ((kt * 32 + lk8) ^ ((lr & 7) << 3))];
            #pragma unroll
            for (int i = 0; i < MT1PW; ++i) {
                const int mt = wid + 4 * i;
                if (mt < MT1) {
                    const bfrag8 afr = *(const bfrag8*)&owpk[
                        (size_t)(mt * 16 + lr) * Rpad + kt * 32 + lk8];
                    #pragma unroll
                    for (int nt = 0; nt < NT; ++nt)
                        acc1[i][nt] = __builtin_amdgcn_mfma_f32_16x16x32_bf16(
                            afr, bfr[nt], acc1[i][nt], 0, 0, 0);
                }
            }
        }
        if (lr < LRLIM) {
            #pragma unroll
            for (int i = 0; i < MT1PW; ++i) {
                const int mt = wid + 4 * i;
                if (mt < MT1) {
                    #pragma unroll
                    for (int nt = 0; nt < NT; ++nt) {
                        const int pix = nt * 16 + lr;
                        #pragma unroll
                        for (int q = 0; q < 4; ++q) {
                            const int ch = mt * 16 + (lane >> 4) * 4 + q;
                            if (ch < P3) {
                                const float v = acc1[i][nt][q] + ob[ch];
                                if (ch < 2 * P) {
                                    const int p = ch >> 1;
                                    if (ch & 1)
                                        s_px[pix][p] = (float)(ix0 + pix * STRIDE
                                                               + p % K) + v;
                                    else
                                        s_py[pix][p] = (float)(iy0 + p / K) + v;
                                } else {
                                    s_mask[pix][ch - 2 * P] =
                                        f2bf(1.0f / (1.0f + __expf(-v)));
                                }
                            }
                        }
                    }
                }
            }
        }
    }
    __syncthreads();   // phase-1 s_u reads drained (lgkmcnt 0) -> reuse as cols

    // ---- phase 2: bilinear sample * mask -> s_u (coords shared
    //      across channels; one item = one (pix,p,changroup) tuple) ----
    {
        constexpr int ITEMS = TILE * P;
        constexpr int CG  = (ITEMS >= 256) ? 1 : (256 / ITEMS);  // chan groups
        constexpr int CPG = CIN / CG;                            // chans/group
        constexpr int PSZ = PROWS * PCOLS;
        const int HW = H * W;
        for (int it = tid; it < ITEMS * CG; it += 256) {
            int item, cg;
            if constexpr (CG == 1) { item = it; cg = 0; }
            else { item = it % ITEMS; cg = it / ITEMS; }
            const int p   = item % P;
            const int pix = item / P;
            const float py = s_py[pix][p];
            const float px = s_px[pix][p];
            const float mk = bf2f(s_mask[pix][p]);
            const float y0f = floorf(py), x0f = floorf(px);
            const float wy = py - y0f, wx = px - x0f;
            const int y0 = (int)y0f, x0 = (int)x0f;
            const int swz = (pix & 7) << 3;
            ushort_t* dst = &s_u[pix * Rpad];
            bool done = false;
            if constexpr (PMODE == 2) {
                const int pyr = y0 - (iy0 - 1);
                const int pxr = x0 - (ix0 - 1);
                if (pyr >= 0 && pyr < PROWS - 1 && pxr >= 0 && pxr < PCOLS - 1) {
                    const float* pp = &s_patchf[(size_t)(cg * CPG) * PSZ
                                                + pyr * PCOLS + pxr];
                    int c = cg * CPG;
                    #pragma unroll
                    for (int ci = 0; ci < CPG; ++ci, ++c) {
                        const float v00 = pp[0], v01 = pp[1];
                        const float v10 = pp[PCOLS], v11 = pp[PCOLS + 1];
                        const float top = v00 + wx * (v01 - v00);
                        const float bot = v10 + wx * (v11 - v10);
                        const float acc = top + wy * (bot - top);
                        dst[(c * P + p) ^ swz] = f2bf(acc * mk);
                        pp += PSZ;
                    }
                    done = true;
                }
            } else if constexpr (PMODE == 3) {
                const int pyr = y0 - (iy0 - 1);
                const int pxr = x0 - (ix0 - 1);
                if (pyr >= 0 && pyr < PROWS - 1 && pxr >= 0 && pxr < PCOLS - 1) {
                    const ushort_t* pp = &s_patchh[(size_t)(cg * CPG) * PSZ
                                                   + pyr * PCOLS + pxr];
                    int c = cg * CPG;
                    #pragma unroll 4
                    for (int ci = 0; ci < CPG; ++ci, ++c) {
                        const float v00 = bf2f(pp[0]), v01 = bf2f(pp[1]);
                        const float v10 = bf2f(pp[PCOLS]), v11 = bf2f(pp[PCOLS + 1]);
                        const float top = v00 + wx * (v01 - v00);
                        const float bot = v10 + wx * (v11 - v10);
                        const float acc = top + wy * (bot - top);
                        dst[(c * P + p) ^ swz] = f2bf(acc * mk);
                        pp += PSZ;
                    }
                    done = true;
                }
            }
            if (!done) {
                if (y0 >= 0 && y0 < H - 1 && x0 >= 0 && x0 < W - 1) {
                    const float* pr = xb + (size_t)(cg * CPG) * HW
                                         + (size_t)y0 * W + x0;
                    int c = cg * CPG;
                    for (int ci = 0; ci < CPG; ++ci, ++c) {
                        const float v00 = pr[0], v01 = pr[1];
                        const float v10 = pr[W], v11 = pr[W + 1];
                        const float top = v00 + wx * (v01 - v00);
                        const float bot = v10 + wx * (v11 - v10);
                        const float acc = top + wy * (bot - top);
                        dst[(c * P + p) ^ swz] = f2bf(acc * mk);
                        pr += HW;
                    }
                } else {
                    const bool y0ok = (y0 >= 0 && y0 < H);
                    const bool y1ok = (y0 + 1 >= 0 && y0 + 1 < H);
                    const bool x0ok = (x0 >= 0 && x0 < W);
                    const bool x1ok = (x0 + 1 >= 0 && x0 + 1 < W);
                    const float w00 = (1.0f - wy) * (1.0f - wx);
                    const float w01 = (1.0f - wy) * wx;
                    const float w10 = wy * (1.0f - wx);
                    const float w11 = wy * wx;
                    const float* xc = xb + (size_t)(cg * CPG) * HW;
                    int c = cg * CPG;
                    for (int ci = 0; ci < CPG; ++ci, ++c) {
                        float acc = 0.0f;
                        if (y0ok) {
                            const float* pr = xc + (size_t)y0 * W + x0;
                            if (x0ok) acc += pr[0] * w00;
                            if (x1ok) acc += pr[1] * w01;
                        }
                        if (y1ok) {
                            const float* pr = xc + (size_t)(y0 + 1) * W + x0;
                            if (x0ok) acc += pr[0] * w10;
                            if (x1ok) acc += pr[1] * w11;
                        }
                        dst[(c * P + p) ^ swz] = f2bf(acc * mk);
                        xc += HW;
                    }
                }
            }
        }
        // zero-fill padded K region
        if constexpr (Rpad != R) {
            for (int idx = tid; idx < (Rpad - R) * TILE; idx += 256) {
                const int r   = R + idx / TILE;
                const int pix = idx % TILE;
                s_u[pix * Rpad + (r ^ ((pix & 7) << 3))] = 0;
            }
        }
    }
    __syncthreads();

    // ---- phase 3: main conv via MFMA ----
    {
        f32x4 acc3[MT3PW][NT] = {};
        for (int kt = 0; kt < KT; ++kt) {
            bfrag8 bfr[NT];
            #pragma unroll
            for (int nt = 0; nt < NT; ++nt)
                bfr[nt] = *(const bfrag8*)&s_u[(nt * 16 + lr) * Rpad +
                              ((kt * 32 + lk8) ^ ((lr & 7) << 3))];
            #pragma unroll
            for (int i = 0; i < MT3PW; ++i) {
                const int mt = wid + 4 * i;
                if (mt < MT3) {
                    const bfrag8 afr = *(const bfrag8*)&wpk[
                        (size_t)(mt * 16 + lr) * Rpad + kt * 32 + lk8];
                    #pragma unroll
                    for (int nt = 0; nt < NT; ++nt)
                        acc3[i][nt] = __builtin_amdgcn_mfma_f32_16x16x32_bf16(
                            afr, bfr[nt], acc3[i][nt], 0, 0, 0);
                }
            }
        }
        if (lr < LRLIM) {
            #pragma unroll
            for (int i = 0; i < MT3PW; ++i) {
                const int mt = wid + 4 * i;
                if (mt < MT3) {
                    #pragma unroll
                    for (int nt = 0; nt < NT; ++nt) {
                        #pragma unroll
                        for (int q = 0; q < 4; ++q) {
                            const int ch = mt * 16 + (lane >> 4) * 4 + q;
                            out[(((size_t)b * COUT + ch) * Ho + oy0) * Wo
                                + ox0 + nt * 16 + lr] = acc3[i][nt][q] + bias[ch];
                        }
                    }
                }
            }
        }
    }
}

// ================= instance norm (one block per (b,c) plane) =================
// float4-vectorized loads/stores (HW is always a multiple of 1024 here).
__global__ __launch_bounds__(256) void in_relu_kernel(float* __restrict__ data,
                                                      int HW, int relu)
{
    float* plane = data + (size_t)blockIdx.x * HW;
    const int tid = threadIdx.x;
    float s = 0.0f, s2 = 0.0f;
    for (int i = tid * 4; i < HW; i += 1024) {
        const float4 v = *(const float4*)&plane[i];
        s  += v.x + v.y + v.z + v.w;
        s2 += v.x * v.x + v.y * v.y + v.z * v.z + v.w * v.w;
    }
    __shared__ float red0[256];
    __shared__ float red1[256];
    red0[tid] = s; red1[tid] = s2;
    __syncthreads();
    for (int off = 128; off > 0; off >>= 1) {
        if (tid < off) { red0[tid] += red0[tid + off]; red1[tid] += red1[tid + off]; }
        __syncthreads();
    }
    const float mean = red0[0] / (float)HW;
    float var = red1[0] / (float)HW - mean * mean;
    var = fmaxf(var, 0.0f);
    const float rstd = rsqrtf(var + EPS);
    for (int i = tid * 4; i < HW; i += 1024) {
        float4 v = *(const float4*)&plane[i];
        v.x = (v.x - mean) * rstd; v.y = (v.y - mean) * rstd;
        v.z = (v.z - mean) * rstd; v.w = (v.w - mean) * rstd;
        if (relu) {
            v.x = fmaxf(v.x, 0.0f); v.y = fmaxf(v.y, 0.0f);
            v.z = fmaxf(v.z, 0.0f); v.w = fmaxf(v.w, 0.0f);
        }
        *(float4*)&plane[i] = v;
    }
}

// h += 0.1 * instance_norm(r)   (in-place on workspace h)
__global__ __launch_bounds__(256) void in_resadd_kernel(float* __restrict__ h,
                                                        const float* __restrict__ r,
                                                        int HW)
{
    const float* plane = r + (size_t)blockIdx.x * HW;
    float* hp = h + (size_t)blockIdx.x * HW;
    const int tid = threadIdx.x;
    float s = 0.0f, s2 = 0.0f;
    for (int i = tid * 4; i < HW; i += 1024) {
        const float4 v = *(const float4*)&plane[i];
        s  += v.x + v.y + v.z + v.w;
        s2 += v.x * v.x + v.y * v.y + v.z * v.z + v.w * v.w;
    }
    __shared__ float red0[256];
    __shared__ float red1[256];
    red0[tid] = s; red1[tid] = s2;
    __syncthreads();
    for (int off = 128; off > 0; off >>= 1) {
        if (tid < off) { red0[tid] += red0[tid + off]; red1[tid] += red1[tid + off]; }
        __syncthreads();
    }
    const float mean = red0[0] / (float)HW;
    float var = red1[0] / (float)HW - mean * mean;
    var = fmaxf(var, 0.0f);
    const float rstd = rsqrtf(var + EPS);
    for (int i = tid * 4; i < HW; i += 1024) {
        const float4 v = *(const float4*)&plane[i];
        float4 o = *(const float4*)&hp[i];
        o.x += 0.1f * ((v.x - mean) * rstd);
        o.y += 0.1f * ((v.y - mean) * rstd);
        o.z += 0.1f * ((v.z - mean) * rstd);
        o.w += 0.1f * ((v.w - mean) * rstd);
        *(float4*)&hp[i] = o;
    }
}

// dst = h + 0.1 * instance_norm(r)   (d_out written exactly once at the end)
__global__ __launch_bounds__(256) void in_resadd_out_kernel(
    float* __restrict__ dst, const float* __restrict__ h,
    const float* __restrict__ r, int HW)
{
    const float* plane = r + (size_t)blockIdx.x * HW;
    const float* hp = h + (size_t)blockIdx.x * HW;
    float* dp = dst + (size_t)blockIdx.x * HW;
    const int tid = threadIdx.x;
    float s = 0.0f, s2 = 0.0f;
    for (int i = tid * 4; i < HW; i += 1024) {
        const float4 v = *(const float4*)&plane[i];
        s  += v.x + v.y + v.z + v.w;
        s2 += v.x * v.x + v.y * v.y + v.z * v.z + v.w * v.w;
    }
    __shared__ float red0[256];
    __shared__ float red1[256];
    red0[tid] = s; red1[tid] = s2;
    __syncthreads();
    for (int off = 128; off > 0; off >>= 1) {
        if (tid < off) { red0[tid] += red0[tid + off]; red1[tid] += red1[tid + off]; }
        __syncthreads();
    }
    const float mean = red0[0] / (float)HW;
    float var = red1[0] / (float)HW - mean * mean;
    var = fmaxf(var, 0.0f);
    const float rstd = rsqrtf(var + EPS);
    for (int i = tid * 4; i < HW; i += 1024) {
        const float4 v = *(const float4*)&plane[i];
        const float4 o = *(const float4*)&hp[i];
        float4 d;
        d.x = o.x + 0.1f * ((v.x - mean) * rstd);
        d.y = o.y + 0.1f * ((v.y - mean) * rstd);
        d.z = o.z + 0.1f * ((v.z - mean) * rstd);
        d.w = o.w + 0.1f * ((v.w - mean) * rstd);
        *(float4*)&dp[i] = d;
    }
}

// ================= res-conv path: tiled im2col + bf16 MFMA GEMM =============
__global__ __launch_bounds__(256) void im2col_tiled_kernel(
    const float* __restrict__ in, ushort_t* __restrict__ cols)
{
    // grid = 8 b * 32 y * 4 cgroups = 1024
    const int bid = blockIdx.x;
    const int cg = bid & 3;
    const int y  = (bid >> 2) & 31;
    const int b  = bid >> 7;
    const int c0 = cg * 64;
    const int tid = threadIdx.x;

    __shared__ float s_p[64 * 3 * 34];   // [c][row][x], 26.1 KB

    // phase A: stage input slab (zero-padded)
    for (int idx = tid; idx < 64 * 3 * 34; idx += 256) {
        const int c   = idx / 102;
        const int rem = idx % 102;
        const int r   = rem / 34;
        const int xx  = rem % 34;
        const int yy = y + r - 1;
        const int gx = xx - 1;
        float v = 0.0f;
        if (yy >= 0 && yy < 32 && gx >= 0 && gx < 32)
            v = in[(((size_t)b * 256 + c0 + c) * 32 + yy) * 32 + gx];
        s_p[idx] = v;
    }
    __syncthreads();

    // phase B: 32 xout * 16 c-quads = 512 items
    for (int it = tid; it < 512; it += 256) {
        const int xout = it >> 4;
        const int cq   = (it & 15) * 4;          // local c, multiple of 4
        const int n = b * 1024 + y * 32 + xout;
        ushort_t* oc = cols + (size_t)n * 2304 + (size_t)(c0 + cq) * 9;
        ushort_t tmp[36];
        #pragma unroll
        for (int ci = 0; ci < 4; ++ci)
            #pragma unroll
            for (int ky = 0; ky < 3; ++ky)
                #pragma unroll
                for (int kx = 0; kx < 3; ++kx)
                    tmp[ci * 9 + ky * 3 + kx] =
                        f2bf(s_p[(cq + ci) * 102 + ky * 34 + xout + kx]);
        #pragma unroll
        for (int i2 = 0; i2 < 9; ++i2) {
            unsigned long long w =
                  (unsigned long long)tmp[4 * i2]
                | ((unsigned long long)tmp[4 * i2 + 1] << 16)
                | ((unsigned long long)tmp[4 * i2 + 2] << 32)
                | ((unsigned long long)tmp[4 * i2 + 3] << 48);
            *((unsigned long long*)oc + i2) = w;   // 8B-aligned: (c0+cq)%4==0
        }
    }
}

__global__ __launch_bounds__(256) void f32_to_bf16_kernel(
    const float* __restrict__ in, ushort_t* __restrict__ out, int n)
{
    const int i = blockIdx.x * 256 + threadIdx.x;
    if (i < n) out[i] = f2bf(in[i]);
}

// C[m][n] = bias[m] + sum_k A[m][k]*Bt[n][k]; A,Bt bf16 K-contiguous.
// BM=64, BN=128, BK=64 (36 iters): 32 MFMAs per barrier-pair.
// LDS pad +8: row stride 144B -> r*36 mod 32 = r*4 -> only 2-way alias (free).
__global__ __launch_bounds__(256) void gemm_bf16_kernel(
    const ushort_t* __restrict__ A,   // [256][2304]
    const ushort_t* __restrict__ Bt,  // [8192][2304]
    const float* __restrict__ bias,   // [256]
    float* __restrict__ C)            // [8][256][1024], n=b*1024+pix
{
    constexpr int Kt = 2304;
    __shared__ ushort_t sA[64][72];
    __shared__ ushort_t sB[128][72];

    const int m0 = blockIdx.x * 64;
    const int n0 = blockIdx.y * 128;
    const int tid  = threadIdx.x;
    const int wid  = tid >> 6, lane = tid & 63;
    const int wm = wid >> 1, wn = wid & 1;
    const int lr = lane & 15, lk = (lane >> 4) * 8;

    // staging map: chunk -> (row = c>>3, seg = c&7); A has 512 int4, B 1024.
    const int srow = tid >> 3, sseg = (tid & 7) * 8;
    const ushort_t* ap0 = A  + (size_t)(m0 + srow) * Kt + sseg;
    const ushort_t* ap1 = A  + (size_t)(m0 + 32 + srow) * Kt + sseg;
    const ushort_t* bp0 = Bt + (size_t)(n0 + srow) * Kt + sseg;
    const ushort_t* bp1 = Bt + (size_t)(n0 + 32 + srow) * Kt + sseg;
    const ushort_t* bp2 = Bt + (size_t)(n0 + 64 + srow) * Kt + sseg;
    const ushort_t* bp3 = Bt + (size_t)(n0 + 96 + srow) * Kt + sseg;

    f32x4 acc[2][4] = {};

    for (int k0 = 0; k0 < Kt; k0 += 64) {
        __syncthreads();                       // prev iteration's reads done
        *(int4*)&sA[srow][sseg]      = *(const int4*)(ap0 + k0);
        *(int4*)&sA[32 + srow][sseg] = *(const int4*)(ap1 + k0);
        *(int4*)&sB[srow][sseg]      = *(const int4*)(bp0 + k0);
        *(int4*)&sB[32 + srow][sseg] = *(const int4*)(bp1 + k0);
        *(int4*)&sB[64 + srow][sseg] = *(const int4*)(bp2 + k0);
        *(int4*)&sB[96 + srow][sseg] = *(const int4*)(bp3 + k0);
        __syncthreads();                       // staging visible

        #pragma unroll
        for (int ks = 0; ks < 2; ++ks) {
            bfrag8 af[2], bf[4];
            #pragma unroll
            for (int mi = 0; mi < 2; ++mi)
                af[mi] = *(const bfrag8*)&sA[wm * 32 + mi * 16 + lr][ks * 32 + lk];
            #pragma unroll
            for (int nj = 0; nj < 4; ++nj)
                bf[nj] = *(const bfrag8*)&sB[wn * 64 + nj * 16 + lr][ks * 32 + lk];
            #pragma unroll
            for (int mi = 0; mi < 2; ++mi)
                #pragma unroll
                for (int nj = 0; nj < 4; ++nj)
                    acc[mi][nj] = __builtin_amdgcn_mfma_f32_16x16x32_bf16(
                        af[mi], bf[nj], acc[mi][nj], 0, 0, 0);
        }
    }

    #pragma unroll
    for (int mi = 0; mi < 2; ++mi) {
        #pragma unroll
        for (int nj = 0; nj < 4; ++nj) {
            const int n = n0 + wn * 64 + nj * 16 + lr;
            const int b = n >> 10, pix = n & 1023;
            #pragma unroll
            for (int r = 0; r < 4; ++r) {
                const int m = m0 + wm * 32 + mi * 16 + (lane >> 4) * 4 + r;
                C[(((size_t)b * 256 + m) << 10) + pix] = acc[mi][nj][r] + bias[m];
            }
        }
    }
}

// ================= launch =================
extern "C" void kernel_launch(void* const* d_in, const int* in_sizes, int n_in,
                              void* d_out, int out_size, void* d_ws, size_t ws_size,
                              hipStream_t stream)
{
    const float* x    = (const float*)d_in[0];
    const float* d1w  = (const float*)d_in[1];
    const float* d1b  = (const float*)d_in[2];
    const float* d1ow = (const float*)d_in[3];
    const float* d1ob = (const float*)d_in[4];
    const float* d2w  = (const float*)d_in[5];
    const float* d2b  = (const float*)d_in[6];
    const float* d2ow = (const float*)d_in[7];
    const float* d2ob = (const float*)d_in[8];
    const float* d3w  = (const float*)d_in[9];
    const float* d3b  = (const float*)d_in[10];
    const float* d3ow = (const float*)d_in[11];
    const float* d3ob = (const float*)d_in[12];
    const float* d4w  = (const float*)d_in[13];
    const float* d4b  = (const float*)d_in[14];
    const float* d4ow = (const float*)d_in[15];
    const float* d4ob = (const float*)d_in[16];
    const float* resw = (const float*)d_in[17];
    const float* resb = (const float*)d_in[18];

    float* A   = (float*)d_ws;          // [0 .. 16,777,216) floats
    float* Bb  = A + 16777216;          // [16,777,216 .. 25,165,824) floats
    float* out = (float*)d_out;         // 8x256x32x32, write-once at the end

    // dcn weight packs live in d_out's bytes (free scratch: d_out is fully
    // overwritten by the final kernel). 897,024 ushorts = 1.79 MB < 8.4 MB.
    ushort_t* pk = (ushort_t*)d_out;
    ushort_t* ow1 = pk;                 // 160*192
    ushort_t* w1  = ow1 + 160 * 192;    // 32*192
    ushort_t* ow2 = w1  + 32 * 192;     // 48*512
    ushort_t* w2  = ow2 + 48 * 512;     // 64*512
    ushort_t* ow3 = w2  + 64 * 512;     // 48*1024
    ushort_t* w3  = ow3 + 48 * 1024;    // 128*1024
    ushort_t* ow4 = w3  + 128 * 1024;   // 48*2048
    ushort_t* w4  = ow4 + 48 * 2048;    // 256*2048

    // workspace sub-regions for the res phase:
    float* r    = A;                                   // [0 .. 2,097,152)
    float* r2   = A + 2097152;
    ushort_t* cols = (ushort_t*)(A + 4194304);         // 8192*2304 bf16
    ushort_t* wbf  = (ushort_t*)Bb;                    // 4*589,824 bf16
    float* H4   = Bb + 4194304;                        // 2,097,152 floats

    const int B = 8;

    // ---- weight prepack (bf16, K-padded) ----
    pack_w_kernel<<<(160 * 192 + 255) / 256, 256, 0, stream>>>(d1ow, ow1, 147, 147, 160, 192);
    pack_w_kernel<<<(32 * 192 + 255) / 256, 256, 0, stream>>>(d1w, w1, 32, 147, 32, 192);
    pack_w_kernel<<<(48 * 512 + 255) / 256, 256, 0, stream>>>(d2ow, ow2, 48, 512, 48, 512);
    pack_w_kernel<<<(64 * 512 + 255) / 256, 256, 0, stream>>>(d2w, w2, 64, 512, 64, 512);
    pack_w_kernel<<<(48 * 1024 + 255) / 256, 256, 0, stream>>>(d3ow, ow3, 48, 1024, 48, 1024);
    pack_w_kernel<<<(128 * 1024 + 255) / 256, 256, 0, stream>>>(d3w, w3, 128, 1024, 128, 1024);
    pack_w_kernel<<<(48 * 2048 + 255) / 256, 256, 0, stream>>>(d4ow, ow4, 48, 2048, 48, 2048);
    pack_w_kernel<<<(256 * 2048 + 255) / 256, 256, 0, stream>>>(d4w, w4, 256, 2048, 256, 2048);

    // dcn1: 3->32, K=7 s=1 p=3; 256x256  (NT=2, fp32 halo patch + bf16 mask)
    dcn_mfma_kernel<3, 32, 7, 1, 3, 32, 2><<<B * (256 * 256 / 32), 256, 0, stream>>>(
        x, 256, 256, w1, d1b, ow1, d1ob, A, 256, 256);
    in_relu_kernel<<<B * 32, 256, 0, stream>>>(A, 65536, 1);

    // dcn2: 32->64, K=4 s=2 p=1; 256 -> 128  (bf16 halo patch; ~32.8 KB)
    dcn_mfma_kernel<32, 64, 4, 2, 1, 16, 3><<<B * (128 * 128 / 16), 256, 0, stream>>>(
        A, 256, 256, w2, d2b, ow2, d2ob, Bb, 128, 128);
    in_relu_kernel<<<B * 64, 256, 0, stream>>>(Bb, 16384, 1);

    // dcn3: 64->128, K=4 s=2 p=1; 128 -> 64  (bf16 halo patch, TILE=8; ~33 KB)
    dcn_mfma_kernel<64, 128, 4, 2, 1, 8, 3><<<B * (64 * 64 / 8), 256, 0, stream>>>(
        Bb, 128, 128, w3, d3b, ow3, d3ob, A, 64, 64);
    in_relu_kernel<<<B * 128, 256, 0, stream>>>(A, 4096, 1);

    // dcn4: 128->256, K=4 s=2 p=1; 64 -> 32 -> H4  (patchless TILE=8; ~34 KB)
    dcn_mfma_kernel<128, 256, 4, 2, 1, 8, 0><<<B * (32 * 32 / 8), 256, 0, stream>>>(
        A, 64, 64, w4, d4b, ow4, d4ob, H4, 32, 32);
    in_relu_kernel<<<B * 256, 256, 0, stream>>>(H4, 1024, 1);

    // --- residual blocks via bf16 MFMA GEMM ---
    f32_to_bf16_kernel<<<(4 * 589824 + 255) / 256, 256, 0, stream>>>(
        resw, wbf, 4 * 589824);

    dim3 ggrid(4, 64);
    // i = 0 : h (H4) updated in place
    im2col_tiled_kernel<<<1024, 256, 0, stream>>>(H4, cols);
    gemm_bf16_kernel<<<ggrid, 256, 0, stream>>>(
        wbf + (size_t)0 * 589824, cols, resb + 0 * 256, r);
    in_relu_kernel<<<B * 256, 256, 0, stream>>>(r, 1024, 1);
    im2col_tiled_kernel<<<1024, 256, 0, stream>>>(r, cols);
    gemm_bf16_kernel<<<ggrid, 256, 0, stream>>>(
        wbf + (size_t)1 * 589824, cols, resb + 1 * 256, r2);
    in_resadd_kernel<<<B * 256, 256, 0, stream>>>(H4, r2, 1024);

    // i = 1 : final result goes straight to d_out (write-once, covers packs)
    im2col_tiled_kernel<<<1024, 256, 0, stream>>>(H4, cols);
    gemm_bf16_kernel<<<ggrid, 256, 0, stream>>>(
        wbf + (size_t)2 * 589824, cols, resb + 2 * 256, r);
    in_relu_kernel<<<B * 256, 256, 0, stream>>>(r, 1024, 1);
    im2col_tiled_kernel<<<1024, 256, 0, stream>>>(r, cols);
    gemm_bf16_kernel<<<ggrid, 256, 0, stream>>>(
        wbf + (size_t)3 * 589824, cols, resb + 3 * 256, r2);
    in_resadd_out_kernel<<<B * 256, 256, 0, stream>>>(out, H4, r2, 1024);
}

// Round 18
// 1246.800 us; speedup vs baseline: 1.0612x; 1.0612x over previous
//
#include <hip/hip_runtime.h>
#include <hip/hip_bf16.h>
#include <math.h>

#define EPS 1e-5f

typedef short bfrag8 __attribute__((ext_vector_type(8)));   // 8 bf16 (4 VGPRs)
typedef float f32x4 __attribute__((ext_vector_type(4)));
typedef unsigned short ushort_t;

__device__ inline ushort_t f2bf(float f) {
    __hip_bfloat16 h = __float2bfloat16(f);
    return *reinterpret_cast<ushort_t*>(&h);
}
__device__ inline float bf2f(ushort_t u) {
    unsigned int v = ((unsigned int)u) << 16;
    float f;
    __builtin_memcpy(&f, &v, 4);
    return f;
}

// ====== weight prepack: fp32 [M][R] -> bf16 [Mpad][Rpad] (zero-padded) ======
__global__ __launch_bounds__(256) void pack_w_kernel(
    const float* __restrict__ src, ushort_t* __restrict__ dst,
    int M, int R, int Mpad, int Rpad)
{
    const int idx = blockIdx.x * 256 + threadIdx.x;
    if (idx >= Mpad * Rpad) return;
    const int m = idx / Rpad, r = idx % Rpad;
    float v = 0.0f;
    if (m < M && r < R) v = src[(size_t)m * R + r];
    dst[idx] = f2bf(v);
}

// ================= fused modulated-deformable-conv stage (MFMA) =============
// One block (256 thr = 4 waves) per TILE consecutive output pixels (one row,
// NT = TILE/16 MFMA n-tiles, LRLIM = min(TILE,16)).
// PMODE 0: global im2col + global bilinear                     (dcn4)
// PMODE 2: fp32 halo patch, phase0b + LDS phase2 bilinear     (dcn1)
// PMODE 3: bf16 halo patch, phase0b + LDS phase2 bilinear     (dcn2, dcn3)
// Halo = 1 px; samples outside the patch fall back to exact global path.
// s_u is a UNION: im2col operand for phase1, then cols for phase3; the
// __syncthreads at each boundary implies lgkmcnt(0) -> race-free.
// r17 lesson: quad-packed ds_write_b64 in phase 0b INCREASED bank conflicts
// (19.8M vs 16.6M) and regressed 26% -- scalar expand restored.
template<int CIN, int COUT, int K, int STRIDE, int PAD, int TILE, int PMODE>
__global__ __launch_bounds__(256, 4) void dcn_mfma_kernel(
    const float* __restrict__ x, int H, int W,
    const ushort_t* __restrict__ wpk,   // [COUT][Rpad] bf16
    const float* __restrict__ bias,     // [COUT]
    const ushort_t* __restrict__ owpk,  // [M1pad][Rpad] bf16
    const float* __restrict__ ob,       // [3P]
    float* __restrict__ out, int Ho, int Wo)
{
    constexpr int P     = K * K;
    constexpr int P3    = 3 * P;
    constexpr int R     = CIN * P;
    constexpr int Rpad  = (R + 63) & ~63;
    constexpr int KT    = Rpad / 32;
    constexpr int NT    = (TILE + 15) / 16;   // MFMA n-tiles
    constexpr int MT1   = (P3 + 15) / 16;     // m-tiles, offset conv
    constexpr int MT1PW = (MT1 + 3) / 4;
    constexpr int MT3   = COUT / 16;          // m-tiles, main conv
    constexpr int MT3PW = (MT3 + 3) / 4;
    constexpr int COLS  = (TILE - 1) * STRIDE + K;
    constexpr int PROWS = K + 2;              // halo rows (modes 2/3)
    constexpr int PCOLS = COLS + 2;           // halo cols (modes 2/3)
    constexpr int PELN  = CIN * PROWS * PCOLS;
    // raw patch buffer in 32-bit units (fp32 for PMODE2, bf16 for PMODE3)
    constexpr int P32   = (PMODE == 2) ? PELN : (PMODE == 3) ? (PELN + 1) / 2 : 1;
    constexpr int LRLIM = (TILE < 16) ? TILE : 16;

    __shared__ unsigned int s_patch32[P32];
    __shared__ ushort_t s_u[TILE * Rpad];     // union: pc (ph0b/1), cols (ph2/3)
    __shared__ float s_py[TILE][P];
    __shared__ float s_px[TILE][P];
    __shared__ ushort_t s_mask[TILE][P];      // bf16

    ushort_t* s_patchh = (ushort_t*)s_patch32;
    float*    s_patchf = (float*)s_patch32;

    const int tilesPerImg = (Ho * Wo) / TILE;
    const int b    = blockIdx.x / tilesPerImg;
    const int tile = blockIdx.x % tilesPerImg;
    const int base = tile * TILE;             // TILE | Wo -> single output row
    const int tid  = threadIdx.x;
    const int wid  = tid >> 6, lane = tid & 63;
    const int lr   = lane & 15;               // fragment row / pixel column
    const int lk8  = (lane >> 4) * 8;         // fragment K offset (elements)

    const int oy0 = base / Wo;
    const int ox0 = base % Wo;
    const int iy0 = oy0 * STRIDE - PAD;
    const int ix0 = ox0 * STRIDE - PAD;

    const float* xb = x + (size_t)b * CIN * H * W;

    // ---- phase 0a: halo patch -> LDS ----
    if constexpr (PMODE == 2 || PMODE == 3) {
        for (int idx = tid; idx < PELN; idx += 256) {
            const int c   = idx / (PROWS * PCOLS);
            const int rem = idx % (PROWS * PCOLS);
            const int pr  = rem / PCOLS;
            const int pc_ = rem % PCOLS;
            const int iy = iy0 - 1 + pr, ix = ix0 - 1 + pc_;
            float v = 0.0f;
            if (iy >= 0 && iy < H && ix >= 0 && ix < W)
                v = xb[(size_t)c * H * W + iy * W + ix];
            if constexpr (PMODE == 2) s_patchf[idx] = v;
            else                      s_patchh[idx] = f2bf(v);
        }
        __syncthreads();
    }

    // ---- phase 0b: im2col expand -> s_u (thread<->rr, loop pix) ----
    for (int rr = tid; rr < Rpad; rr += 256) {
        if (rr < R) {
            const int c = rr / P, p = rr % P;
            const int ky = p / K, kx = p % K;
            if constexpr (PMODE == 2) {
                const float* srcrow =
                    &s_patchf[(c * PROWS + ky + 1) * PCOLS + kx + 1];
                #pragma unroll 4
                for (int pix = 0; pix < TILE; ++pix)
                    s_u[pix * Rpad + (rr ^ ((pix & 7) << 3))] =
                        f2bf(srcrow[pix * STRIDE]);
            } else if constexpr (PMODE == 3) {
                const ushort_t* srcrow =
                    &s_patchh[(c * PROWS + ky + 1) * PCOLS + kx + 1];
                #pragma unroll 4
                for (int pix = 0; pix < TILE; ++pix)
                    s_u[pix * Rpad + (rr ^ ((pix & 7) << 3))] =
                        srcrow[pix * STRIDE];
            } else {
                const int iy = iy0 + ky;
                const bool rowok = (iy >= 0 && iy < H);
                const float* xrow = xb + (size_t)c * H * W +
                                    (size_t)(rowok ? iy : 0) * W;
                #pragma unroll 4
                for (int pix = 0; pix < TILE; ++pix) {
                    const int ix = ix0 + pix * STRIDE + kx;
                    float v = 0.0f;
                    if (rowok && ix >= 0 && ix < W) v = xrow[ix];
                    s_u[pix * Rpad + (rr ^ ((pix & 7) << 3))] = f2bf(v);
                }
            }
        } else {
            #pragma unroll 4
            for (int pix = 0; pix < TILE; ++pix)
                s_u[pix * Rpad + (rr ^ ((pix & 7) << 3))] = 0;
        }
    }
    __syncthreads();

    // ---- phase 1: offset conv via MFMA; fused-coord epilogue ----
    {
        f32x4 acc1[MT1PW][NT] = {};
        for (int kt = 0; kt < KT; ++kt) {
            bfrag8 bfr[NT];
            #pragma unroll
            for (int nt = 0; nt < NT; ++nt)
                bfr[nt] = *(const bfrag8*)&s_u[(nt * 16 + lr) * Rpad +
                              ((kt * 32 + lk8) ^ ((lr & 7) << 3))];
            #pragma unroll
            for (int i = 0; i < MT1PW; ++i) {
                const int mt = wid + 4 * i;
                if (mt < MT1) {
                    const bfrag8 afr = *(const bfrag8*)&owpk[
                        (size_t)(mt * 16 + lr) * Rpad + kt * 32 + lk8];
                    #pragma unroll
                    for (int nt = 0; nt < NT; ++nt)
                        acc1[i][nt] = __builtin_amdgcn_mfma_f32_16x16x32_bf16(
                            afr, bfr[nt], acc1[i][nt], 0, 0, 0);
                }
            }
        }
        if (lr < LRLIM) {
            #pragma unroll
            for (int i = 0; i < MT1PW; ++i) {
                const int mt = wid + 4 * i;
                if (mt < MT1) {
                    #pragma unroll
                    for (int nt = 0; nt < NT; ++nt) {
                        const int pix = nt * 16 + lr;
                        #pragma unroll
                        for (int q = 0; q < 4; ++q) {
                            const int ch = mt * 16 + (lane >> 4) * 4 + q;
                            if (ch < P3) {
                                const float v = acc1[i][nt][q] + ob[ch];
                                if (ch < 2 * P) {
                                    const int p = ch >> 1;
                                    if (ch & 1)
                                        s_px[pix][p] = (float)(ix0 + pix * STRIDE
                                                               + p % K) + v;
                                    else
                                        s_py[pix][p] = (float)(iy0 + p / K) + v;
                                } else {
                                    s_mask[pix][ch - 2 * P] =
                                        f2bf(1.0f / (1.0f + __expf(-v)));
                                }
                            }
                        }
                    }
                }
            }
        }
    }
    __syncthreads();   // phase-1 s_u reads drained (lgkmcnt 0) -> reuse as cols

    // ---- phase 2: bilinear sample * mask -> s_u (coords shared
    //      across channels; one item = one (pix,p,changroup) tuple) ----
    {
        constexpr int ITEMS = TILE * P;
        constexpr int CG  = (ITEMS >= 256) ? 1 : (256 / ITEMS);  // chan groups
        constexpr int CPG = CIN / CG;                            // chans/group
        constexpr int PSZ = PROWS * PCOLS;
        const int HW = H * W;
        for (int it = tid; it < ITEMS * CG; it += 256) {
            int item, cg;
            if constexpr (CG == 1) { item = it; cg = 0; }
            else { item = it % ITEMS; cg = it / ITEMS; }
            const int p   = item % P;
            const int pix = item / P;
            const float py = s_py[pix][p];
            const float px = s_px[pix][p];
            const float mk = bf2f(s_mask[pix][p]);
            const float y0f = floorf(py), x0f = floorf(px);
            const float wy = py - y0f, wx = px - x0f;
            const int y0 = (int)y0f, x0 = (int)x0f;
            const int swz = (pix & 7) << 3;
            ushort_t* dst = &s_u[pix * Rpad];
            bool done = false;
            if constexpr (PMODE == 2) {
                const int pyr = y0 - (iy0 - 1);
                const int pxr = x0 - (ix0 - 1);
                if (pyr >= 0 && pyr < PROWS - 1 && pxr >= 0 && pxr < PCOLS - 1) {
                    const float* pp = &s_patchf[(size_t)(cg * CPG) * PSZ
                                                + pyr * PCOLS + pxr];
                    int c = cg * CPG;
                    #pragma unroll
                    for (int ci = 0; ci < CPG; ++ci, ++c) {
                        const float v00 = pp[0], v01 = pp[1];
                        const float v10 = pp[PCOLS], v11 = pp[PCOLS + 1];
                        const float top = v00 + wx * (v01 - v00);
                        const float bot = v10 + wx * (v11 - v10);
                        const float acc = top + wy * (bot - top);
                        dst[(c * P + p) ^ swz] = f2bf(acc * mk);
                        pp += PSZ;
                    }
                    done = true;
                }
            } else if constexpr (PMODE == 3) {
                const int pyr = y0 - (iy0 - 1);
                const int pxr = x0 - (ix0 - 1);
                if (pyr >= 0 && pyr < PROWS - 1 && pxr >= 0 && pxr < PCOLS - 1) {
                    const ushort_t* pp = &s_patchh[(size_t)(cg * CPG) * PSZ
                                                   + pyr * PCOLS + pxr];
                    int c = cg * CPG;
                    #pragma unroll 4
                    for (int ci = 0; ci < CPG; ++ci, ++c) {
                        const float v00 = bf2f(pp[0]), v01 = bf2f(pp[1]);
                        const float v10 = bf2f(pp[PCOLS]), v11 = bf2f(pp[PCOLS + 1]);
                        const float top = v00 + wx * (v01 - v00);
                        const float bot = v10 + wx * (v11 - v10);
                        const float acc = top + wy * (bot - top);
                        dst[(c * P + p) ^ swz] = f2bf(acc * mk);
                        pp += PSZ;
                    }
                    done = true;
                }
            }
            if (!done) {
                if (y0 >= 0 && y0 < H - 1 && x0 >= 0 && x0 < W - 1) {
                    const float* pr = xb + (size_t)(cg * CPG) * HW
                                         + (size_t)y0 * W + x0;
                    int c = cg * CPG;
                    for (int ci = 0; ci < CPG; ++ci, ++c) {
                        const float v00 = pr[0], v01 = pr[1];
                        const float v10 = pr[W], v11 = pr[W + 1];
                        const float top = v00 + wx * (v01 - v00);
                        const float bot = v10 + wx * (v11 - v10);
                        const float acc = top + wy * (bot - top);
                        dst[(c * P + p) ^ swz] = f2bf(acc * mk);
                        pr += HW;
                    }
                } else {
                    const bool y0ok = (y0 >= 0 && y0 < H);
                    const bool y1ok = (y0 + 1 >= 0 && y0 + 1 < H);
                    const bool x0ok = (x0 >= 0 && x0 < W);
                    const bool x1ok = (x0 + 1 >= 0 && x0 + 1 < W);
                    const float w00 = (1.0f - wy) * (1.0f - wx);
                    const float w01 = (1.0f - wy) * wx;
                    const float w10 = wy * (1.0f - wx);
                    const float w11 = wy * wx;
                    const float* xc = xb + (size_t)(cg * CPG) * HW;
                    int c = cg * CPG;
                    for (int ci = 0; ci < CPG; ++ci, ++c) {
                        float acc = 0.0f;
                        if (y0ok) {
                            const float* pr = xc + (size_t)y0 * W + x0;
                            if (x0ok) acc += pr[0] * w00;
                            if (x1ok) acc += pr[1] * w01;
                        }
                        if (y1ok) {
                            const float* pr = xc + (size_t)(y0 + 1) * W + x0;
                            if (x0ok) acc += pr[0] * w10;
                            if (x1ok) acc += pr[1] * w11;
                        }
                        dst[(c * P + p) ^ swz] = f2bf(acc * mk);
                        xc += HW;
                    }
                }
            }
        }
        // zero-fill padded K region
        if constexpr (Rpad != R) {
            for (int idx = tid; idx < (Rpad - R) * TILE; idx += 256) {
                const int r   = R + idx / TILE;
                const int pix = idx % TILE;
                s_u[pix * Rpad + (r ^ ((pix & 7) << 3))] = 0;
            }
        }
    }
    __syncthreads();

    // ---- phase 3: main conv via MFMA ----
    {
        f32x4 acc3[MT3PW][NT] = {};
        for (int kt = 0; kt < KT; ++kt) {
            bfrag8 bfr[NT];
            #pragma unroll
            for (int nt = 0; nt < NT; ++nt)
                bfr[nt] = *(const bfrag8*)&s_u[(nt * 16 + lr) * Rpad +
                              ((kt * 32 + lk8) ^ ((lr & 7) << 3))];
            #pragma unroll
            for (int i = 0; i < MT3PW; ++i) {
                const int mt = wid + 4 * i;
                if (mt < MT3) {
                    const bfrag8 afr = *(const bfrag8*)&wpk[
                        (size_t)(mt * 16 + lr) * Rpad + kt * 32 + lk8];
                    #pragma unroll
                    for (int nt = 0; nt < NT; ++nt)
                        acc3[i][nt] = __builtin_amdgcn_mfma_f32_16x16x32_bf16(
                            afr, bfr[nt], acc3[i][nt], 0, 0, 0);
                }
            }
        }
        if (lr < LRLIM) {
            #pragma unroll
            for (int i = 0; i < MT3PW; ++i) {
                const int mt = wid + 4 * i;
                if (mt < MT3) {
                    #pragma unroll
                    for (int nt = 0; nt < NT; ++nt) {
                        #pragma unroll
                        for (int q = 0; q < 4; ++q) {
                            const int ch = mt * 16 + (lane >> 4) * 4 + q;
                            out[(((size_t)b * COUT + ch) * Ho + oy0) * Wo
                                + ox0 + nt * 16 + lr] = acc3[i][nt][q] + bias[ch];
                        }
                    }
                }
            }
        }
    }
}

// ================= instance norm (one block per (b,c) plane) =================
// float4-vectorized loads/stores (HW is always a multiple of 1024 here).
__global__ __launch_bounds__(256) void in_relu_kernel(float* __restrict__ data,
                                                      int HW, int relu)
{
    float* plane = data + (size_t)blockIdx.x * HW;
    const int tid = threadIdx.x;
    float s = 0.0f, s2 = 0.0f;
    for (int i = tid * 4; i < HW; i += 1024) {
        const float4 v = *(const float4*)&plane[i];
        s  += v.x + v.y + v.z + v.w;
        s2 += v.x * v.x + v.y * v.y + v.z * v.z + v.w * v.w;
    }
    __shared__ float red0[256];
    __shared__ float red1[256];
    red0[tid] = s; red1[tid] = s2;
    __syncthreads();
    for (int off = 128; off > 0; off >>= 1) {
        if (tid < off) { red0[tid] += red0[tid + off]; red1[tid] += red1[tid + off]; }
        __syncthreads();
    }
    const float mean = red0[0] / (float)HW;
    float var = red1[0] / (float)HW - mean * mean;
    var = fmaxf(var, 0.0f);
    const float rstd = rsqrtf(var + EPS);
    for (int i = tid * 4; i < HW; i += 1024) {
        float4 v = *(const float4*)&plane[i];
        v.x = (v.x - mean) * rstd; v.y = (v.y - mean) * rstd;
        v.z = (v.z - mean) * rstd; v.w = (v.w - mean) * rstd;
        if (relu) {
            v.x = fmaxf(v.x, 0.0f); v.y = fmaxf(v.y, 0.0f);
            v.z = fmaxf(v.z, 0.0f); v.w = fmaxf(v.w, 0.0f);
        }
        *(float4*)&plane[i] = v;
    }
}

// h += 0.1 * instance_norm(r)   (in-place on workspace h)
__global__ __launch_bounds__(256) void in_resadd_kernel(float* __restrict__ h,
                                                        const float* __restrict__ r,
                                                        int HW)
{
    const float* plane = r + (size_t)blockIdx.x * HW;
    float* hp = h + (size_t)blockIdx.x * HW;
    const int tid = threadIdx.x;
    float s = 0.0f, s2 = 0.0f;
    for (int i = tid * 4; i < HW; i += 1024) {
        const float4 v = *(const float4*)&plane[i];
        s  += v.x + v.y + v.z + v.w;
        s2 += v.x * v.x + v.y * v.y + v.z * v.z + v.w * v.w;
    }
    __shared__ float red0[256];
    __shared__ float red1[256];
    red0[tid] = s; red1[tid] = s2;
    __syncthreads();
    for (int off = 128; off > 0; off >>= 1) {
        if (tid < off) { red0[tid] += red0[tid + off]; red1[tid] += red1[tid + off]; }
        __syncthreads();
    }
    const float mean = red0[0] / (float)HW;
    float var = red1[0] / (float)HW - mean * mean;
    var = fmaxf(var, 0.0f);
    const float rstd = rsqrtf(var + EPS);
    for (int i = tid * 4; i < HW; i += 1024) {
        const float4 v = *(const float4*)&plane[i];
        float4 o = *(const float4*)&hp[i];
        o.x += 0.1f * ((v.x - mean) * rstd);
        o.y += 0.1f * ((v.y - mean) * rstd);
        o.z += 0.1f * ((v.z - mean) * rstd);
        o.w += 0.1f * ((v.w - mean) * rstd);
        *(float4*)&hp[i] = o;
    }
}

// dst = h + 0.1 * instance_norm(r)   (d_out written exactly once at the end)
__global__ __launch_bounds__(256) void in_resadd_out_kernel(
    float* __restrict__ dst, const float* __restrict__ h,
    const float* __restrict__ r, int HW)
{
    const float* plane = r + (size_t)blockIdx.x * HW;
    const float* hp = h + (size_t)blockIdx.x * HW;
    float* dp = dst + (size_t)blockIdx.x * HW;
    const int tid = threadIdx.x;
    float s = 0.0f, s2 = 0.0f;
    for (int i = tid * 4; i < HW; i += 1024) {
        const float4 v = *(const float4*)&plane[i];
        s  += v.x + v.y + v.z + v.w;
        s2 += v.x * v.x + v.y * v.y + v.z * v.z + v.w * v.w;
    }
    __shared__ float red0[256];
    __shared__ float red1[256];
    red0[tid] = s; red1[tid] = s2;
    __syncthreads();
    for (int off = 128; off > 0; off >>= 1) {
        if (tid < off) { red0[tid] += red0[tid + off]; red1[tid] += red1[tid + off]; }
        __syncthreads();
    }
    const float mean = red0[0] / (float)HW;
    float var = red1[0] / (float)HW - mean * mean;
    var = fmaxf(var, 0.0f);
    const float rstd = rsqrtf(var + EPS);
    for (int i = tid * 4; i < HW; i += 1024) {
        const float4 v = *(const float4*)&plane[i];
        const float4 o = *(const float4*)&hp[i];
        float4 d;
        d.x = o.x + 0.1f * ((v.x - mean) * rstd);
        d.y = o.y + 0.1f * ((v.y - mean) * rstd);
        d.z = o.z + 0.1f * ((v.z - mean) * rstd);
        d.w = o.w + 0.1f * ((v.w - mean) * rstd);
        *(float4*)&dp[i] = d;
    }
}

// ================= res-conv path: tiled im2col + bf16 MFMA GEMM =============
__global__ __launch_bounds__(256) void im2col_tiled_kernel(
    const float* __restrict__ in, ushort_t* __restrict__ cols)
{
    // grid = 8 b * 32 y * 4 cgroups = 1024
    const int bid = blockIdx.x;
    const int cg = bid & 3;
    const int y  = (bid >> 2) & 31;
    const int b  = bid >> 7;
    const int c0 = cg * 64;
    const int tid = threadIdx.x;

    __shared__ float s_p[64 * 3 * 34];   // [c][row][x], 26.1 KB

    // phase A: stage input slab (zero-padded)
    for (int idx = tid; idx < 64 * 3 * 34; idx += 256) {
        const int c   = idx / 102;
        const int rem = idx % 102;
        const int r   = rem / 34;
        const int xx  = rem % 34;
        const int yy = y + r - 1;
        const int gx = xx - 1;
        float v = 0.0f;
        if (yy >= 0 && yy < 32 && gx >= 0 && gx < 32)
            v = in[(((size_t)b * 256 + c0 + c) * 32 + yy) * 32 + gx];
        s_p[idx] = v;
    }
    __syncthreads();

    // phase B: 32 xout * 16 c-quads = 512 items
    for (int it = tid; it < 512; it += 256) {
        const int xout = it >> 4;
        const int cq   = (it & 15) * 4;          // local c, multiple of 4
        const int n = b * 1024 + y * 32 + xout;
        ushort_t* oc = cols + (size_t)n * 2304 + (size_t)(c0 + cq) * 9;
        ushort_t tmp[36];
        #pragma unroll
        for (int ci = 0; ci < 4; ++ci)
            #pragma unroll
            for (int ky = 0; ky < 3; ++ky)
                #pragma unroll
                for (int kx = 0; kx < 3; ++kx)
                    tmp[ci * 9 + ky * 3 + kx] =
                        f2bf(s_p[(cq + ci) * 102 + ky * 34 + xout + kx]);
        #pragma unroll
        for (int i2 = 0; i2 < 9; ++i2) {
            unsigned long long w =
                  (unsigned long long)tmp[4 * i2]
                | ((unsigned long long)tmp[4 * i2 + 1] << 16)
                | ((unsigned long long)tmp[4 * i2 + 2] << 32)
                | ((unsigned long long)tmp[4 * i2 + 3] << 48);
            *((unsigned long long*)oc + i2) = w;   // 8B-aligned: (c0+cq)%4==0
        }
    }
}

__global__ __launch_bounds__(256) void f32_to_bf16_kernel(
    const float* __restrict__ in, ushort_t* __restrict__ out, int n)
{
    const int i = blockIdx.x * 256 + threadIdx.x;
    if (i < n) out[i] = f2bf(in[i]);
}

// C[m][n] = bias[m] + sum_k A[m][k]*Bt[n][k]; A,Bt bf16 K-contiguous.
// BM=64, BN=128, BK=64; 512 threads = 8 waves (2x4 of 32x32 each):
// grid (4,64)=256 blocks = 1 block/CU, but now 2 waves/SIMD (was 1) for
// latency hiding across the staging barrier. LDS 27 KB. 3 int4/thread stage.
__global__ __launch_bounds__(512) void gemm_bf16_kernel(
    const ushort_t* __restrict__ A,   // [256][2304]
    const ushort_t* __restrict__ Bt,  // [8192][2304]
    const float* __restrict__ bias,   // [256]
    float* __restrict__ C)            // [8][256][1024], n=b*1024+pix
{
    constexpr int Kt = 2304;
    __shared__ ushort_t sA[64][72];
    __shared__ ushort_t sB[128][72];

    const int m0 = blockIdx.x * 64;
    const int n0 = blockIdx.y * 128;
    const int tid  = threadIdx.x;
    const int wid  = tid >> 6, lane = tid & 63;   // wid 0..7
    const int wm = wid & 1, wn = wid >> 1;        // 2 x 4 wave grid
    const int lr = lane & 15, lk = (lane >> 4) * 8;

    // staging: A 64 rows x 8 segs = 512 int4; B 128 x 8 = 1024; 3 per thread
    const int srow = tid >> 3, sseg = (tid & 7) * 8;   // srow 0..63
    const ushort_t* ap  = A  + (size_t)(m0 + srow) * Kt + sseg;
    const ushort_t* bp0 = Bt + (size_t)(n0 + srow) * Kt + sseg;
    const ushort_t* bp1 = Bt + (size_t)(n0 + 64 + srow) * Kt + sseg;

    f32x4 acc[2][2] = {};

    for (int k0 = 0; k0 < Kt; k0 += 64) {
        __syncthreads();                       // prev iteration's reads done
        *(int4*)&sA[srow][sseg]      = *(const int4*)(ap + k0);
        *(int4*)&sB[srow][sseg]      = *(const int4*)(bp0 + k0);
        *(int4*)&sB[64 + srow][sseg] = *(const int4*)(bp1 + k0);
        __syncthreads();                       // staging visible

        #pragma unroll
        for (int ks = 0; ks < 2; ++ks) {
            bfrag8 af[2], bf[2];
            #pragma unroll
            for (int mi = 0; mi < 2; ++mi)
                af[mi] = *(const bfrag8*)&sA[wm * 32 + mi * 16 + lr][ks * 32 + lk];
            #pragma unroll
            for (int nj = 0; nj < 2; ++nj)
                bf[nj] = *(const bfrag8*)&sB[wn * 32 + nj * 16 + lr][ks * 32 + lk];
            #pragma unroll
            for (int mi = 0; mi < 2; ++mi)
                #pragma unroll
                for (int nj = 0; nj < 2; ++nj)
                    acc[mi][nj] = __builtin_amdgcn_mfma_f32_16x16x32_bf16(
                        af[mi], bf[nj], acc[mi][nj], 0, 0, 0);
        }
    }

    #pragma unroll
    for (int mi = 0; mi < 2; ++mi) {
        #pragma unroll
        for (int nj = 0; nj < 2; ++nj) {
            const int n = n0 + wn * 32 + nj * 16 + lr;
            const int b = n >> 10, pix = n & 1023;
            #pragma unroll
            for (int r = 0; r < 4; ++r) {
                const int m = m0 + wm * 32 + mi * 16 + (lane >> 4) * 4 + r;
                C[(((size_t)b * 256 + m) << 10) + pix] = acc[mi][nj][r] + bias[m];
            }
        }
    }
}

// ================= launch =================
extern "C" void kernel_launch(void* const* d_in, const int* in_sizes, int n_in,
                              void* d_out, int out_size, void* d_ws, size_t ws_size,
                              hipStream_t stream)
{
    const float* x    = (const float*)d_in[0];
    const float* d1w  = (const float*)d_in[1];
    const float* d1b  = (const float*)d_in[2];
    const float* d1ow = (const float*)d_in[3];
    const float* d1ob = (const float*)d_in[4];
    const float* d2w  = (const float*)d_in[5];
    const float* d2b  = (const float*)d_in[6];
    const float* d2ow = (const float*)d_in[7];
    const float* d2ob = (const float*)d_in[8];
    const float* d3w  = (const float*)d_in[9];
    const float* d3b  = (const float*)d_in[10];
    const float* d3ow = (const float*)d_in[11];
    const float* d3ob = (const float*)d_in[12];
    const float* d4w  = (const float*)d_in[13];
    const float* d4b  = (const float*)d_in[14];
    const float* d4ow = (const float*)d_in[15];
    const float* d4ob = (const float*)d_in[16];
    const float* resw = (const float*)d_in[17];
    const float* resb = (const float*)d_in[18];

    float* A   = (float*)d_ws;          // [0 .. 16,777,216) floats
    float* Bb  = A + 16777216;          // [16,777,216 .. 25,165,824) floats
    float* out = (float*)d_out;         // 8x256x32x32, write-once at the end

    // dcn weight packs live in d_out's bytes (free scratch: d_out is fully
    // overwritten by the final kernel). 897,024 ushorts = 1.79 MB < 8.4 MB.
    ushort_t* pk = (ushort_t*)d_out;
    ushort_t* ow1 = pk;                 // 160*192
    ushort_t* w1  = ow1 + 160 * 192;    // 32*192
    ushort_t* ow2 = w1  + 32 * 192;     // 48*512
    ushort_t* w2  = ow2 + 48 * 512;     // 64*512
    ushort_t* ow3 = w2  + 64 * 512;     // 48*1024
    ushort_t* w3  = ow3 + 48 * 1024;    // 128*1024
    ushort_t* ow4 = w3  + 128 * 1024;   // 48*2048
    ushort_t* w4  = ow4 + 48 * 2048;    // 256*2048

    // workspace sub-regions for the res phase:
    float* r    = A;                                   // [0 .. 2,097,152)
    float* r2   = A + 2097152;
    ushort_t* cols = (ushort_t*)(A + 4194304);         // 8192*2304 bf16
    ushort_t* wbf  = (ushort_t*)Bb;                    // 4*589,824 bf16
    float* H4   = Bb + 4194304;                        // 2,097,152 floats

    const int B = 8;

    // ---- weight prepack (bf16, K-padded) ----
    pack_w_kernel<<<(160 * 192 + 255) / 256, 256, 0, stream>>>(d1ow, ow1, 147, 147, 160, 192);
    pack_w_kernel<<<(32 * 192 + 255) / 256, 256, 0, stream>>>(d1w, w1, 32, 147, 32, 192);
    pack_w_kernel<<<(48 * 512 + 255) / 256, 256, 0, stream>>>(d2ow, ow2, 48, 512, 48, 512);
    pack_w_kernel<<<(64 * 512 + 255) / 256, 256, 0, stream>>>(d2w, w2, 64, 512, 64, 512);
    pack_w_kernel<<<(48 * 1024 + 255) / 256, 256, 0, stream>>>(d3ow, ow3, 48, 1024, 48, 1024);
    pack_w_kernel<<<(128 * 1024 + 255) / 256, 256, 0, stream>>>(d3w, w3, 128, 1024, 128, 1024);
    pack_w_kernel<<<(48 * 2048 + 255) / 256, 256, 0, stream>>>(d4ow, ow4, 48, 2048, 48, 2048);
    pack_w_kernel<<<(256 * 2048 + 255) / 256, 256, 0, stream>>>(d4w, w4, 256, 2048, 256, 2048);

    // dcn1: 3->32, K=7 s=1 p=3; 256x256  (NT=2, fp32 halo patch + bf16 mask)
    dcn_mfma_kernel<3, 32, 7, 1, 3, 32, 2><<<B * (256 * 256 / 32), 256, 0, stream>>>(
        x, 256, 256, w1, d1b, ow1, d1ob, A, 256, 256);
    in_relu_kernel<<<B * 32, 256, 0, stream>>>(A, 65536, 1);

    // dcn2: 32->64, K=4 s=2 p=1; 256 -> 128  (bf16 halo patch; ~32.8 KB)
    dcn_mfma_kernel<32, 64, 4, 2, 1, 16, 3><<<B * (128 * 128 / 16), 256, 0, stream>>>(
        A, 256, 256, w2, d2b, ow2, d2ob, Bb, 128, 128);
    in_relu_kernel<<<B * 64, 256, 0, stream>>>(Bb, 16384, 1);

    // dcn3: 64->128, K=4 s=2 p=1; 128 -> 64  (bf16 halo patch, TILE=8; ~33 KB)
    dcn_mfma_kernel<64, 128, 4, 2, 1, 8, 3><<<B * (64 * 64 / 8), 256, 0, stream>>>(
        Bb, 128, 128, w3, d3b, ow3, d3ob, A, 64, 64);
    in_relu_kernel<<<B * 128, 256, 0, stream>>>(A, 4096, 1);

    // dcn4: 128->256, K=4 s=2 p=1; 64 -> 32 -> H4  (patchless TILE=8; ~34 KB)
    dcn_mfma_kernel<128, 256, 4, 2, 1, 8, 0><<<B * (32 * 32 / 8), 256, 0, stream>>>(
        A, 64, 64, w4, d4b, ow4, d4ob, H4, 32, 32);
    in_relu_kernel<<<B * 256, 256, 0, stream>>>(H4, 1024, 1);

    // --- residual blocks via bf16 MFMA GEMM ---
    f32_to_bf16_kernel<<<(4 * 589824 + 255) / 256, 256, 0, stream>>>(
        resw, wbf, 4 * 589824);

    dim3 ggrid(4, 64);
    // i = 0 : h (H4) updated in place
    im2col_tiled_kernel<<<1024, 256, 0, stream>>>(H4, cols);
    gemm_bf16_kernel<<<ggrid, 512, 0, stream>>>(
        wbf + (size_t)0 * 589824, cols, resb + 0 * 256, r);
    in_relu_kernel<<<B * 256, 256, 0, stream>>>(r, 1024, 1);
    im2col_tiled_kernel<<<1024, 256, 0, stream>>>(r, cols);
    gemm_bf16_kernel<<<ggrid, 512, 0, stream>>>(
        wbf + (size_t)1 * 589824, cols, resb + 1 * 256, r2);
    in_resadd_kernel<<<B * 256, 256, 0, stream>>>(H4, r2, 1024);

    // i = 1 : final result goes straight to d_out (write-once, covers packs)
    im2col_tiled_kernel<<<1024, 256, 0, stream>>>(H4, cols);
    gemm_bf16_kernel<<<ggrid, 512, 0, stream>>>(
        wbf + (size_t)2 * 589824, cols, resb + 2 * 256, r);
    in_relu_kernel<<<B * 256, 256, 0, stream>>>(r, 1024, 1);
    im2col_tiled_kernel<<<1024, 256, 0, stream>>>(r, cols);
    gemm_bf16_kernel<<<ggrid, 512, 0, stream>>>(
        wbf + (size_t)3 * 589824, cols, resb + 3 * 256, r2);
    in_resadd_out_kernel<<<B * 256, 256, 0, stream>>>(out, H4, r2, 1024);
}

// Round 19
// 1230.433 us; speedup vs baseline: 1.0753x; 1.0133x over previous
//
#include <hip/hip_runtime.h>
#include <hip/hip_bf16.h>
#include <math.h>

#define EPS 1e-5f

typedef short bfrag8 __attribute__((ext_vector_type(8)));   // 8 bf16 (4 VGPRs)
typedef float f32x4 __attribute__((ext_vector_type(4)));
typedef unsigned short ushort_t;

__device__ inline ushort_t f2bf(float f) {
    __hip_bfloat16 h = __float2bfloat16(f);
    return *reinterpret_cast<ushort_t*>(&h);
}
__device__ inline float bf2f(ushort_t u) {
    unsigned int v = ((unsigned int)u) << 16;
    float f;
    __builtin_memcpy(&f, &v, 4);
    return f;
}

// ====== weight prepack: fp32 [M][R] -> bf16 [Mpad][Rpad] (zero-padded) ======
__global__ __launch_bounds__(256) void pack_w_kernel(
    const float* __restrict__ src, ushort_t* __restrict__ dst,
    int M, int R, int Mpad, int Rpad)
{
    const int idx = blockIdx.x * 256 + threadIdx.x;
    if (idx >= Mpad * Rpad) return;
    const int m = idx / Rpad, r = idx % Rpad;
    float v = 0.0f;
    if (m < M && r < R) v = src[(size_t)m * R + r];
    dst[idx] = f2bf(v);
}

// ================= fused modulated-deformable-conv stage (MFMA) =============
// One block (256 thr = 4 waves) per TILE consecutive output pixels (one row,
// NT = TILE/16 MFMA n-tiles, LRLIM = min(TILE,16)).
// PMODE 0: global im2col + global bilinear                     (dcn4)
// PMODE 2: fp32 halo patch, phase0b + LDS phase2 bilinear     (dcn1)
// PMODE 3: bf16 halo patch, phase0b + LDS phase2 bilinear     (dcn2, dcn3)
// Halo = 1 px; samples outside the patch fall back to exact global path.
// s_u is a UNION: im2col operand for phase1, then cols for phase3; the
// __syncthreads at each boundary implies lgkmcnt(0) -> race-free.
template<int CIN, int COUT, int K, int STRIDE, int PAD, int TILE, int PMODE>
__global__ __launch_bounds__(256, 4) void dcn_mfma_kernel(
    const float* __restrict__ x, int H, int W,
    const ushort_t* __restrict__ wpk,   // [COUT][Rpad] bf16
    const float* __restrict__ bias,     // [COUT]
    const ushort_t* __restrict__ owpk,  // [M1pad][Rpad] bf16
    const float* __restrict__ ob,       // [3P]
    float* __restrict__ out, int Ho, int Wo)
{
    constexpr int P     = K * K;
    constexpr int P3    = 3 * P;
    constexpr int R     = CIN * P;
    constexpr int Rpad  = (R + 63) & ~63;
    constexpr int KT    = Rpad / 32;
    constexpr int NT    = (TILE + 15) / 16;   // MFMA n-tiles
    constexpr int MT1   = (P3 + 15) / 16;     // m-tiles, offset conv
    constexpr int MT1PW = (MT1 + 3) / 4;
    constexpr int MT3   = COUT / 16;          // m-tiles, main conv
    constexpr int MT3PW = (MT3 + 3) / 4;
    constexpr int COLS  = (TILE - 1) * STRIDE + K;
    constexpr int PROWS = K + 2;              // halo rows (modes 2/3)
    constexpr int PCOLS = COLS + 2;           // halo cols (modes 2/3)
    constexpr int PELN  = CIN * PROWS * PCOLS;
    constexpr int P32   = (PMODE == 2) ? PELN : (PMODE == 3) ? (PELN + 1) / 2 : 1;
    constexpr int LRLIM = (TILE < 16) ? TILE : 16;

    __shared__ unsigned int s_patch32[P32];
    __shared__ ushort_t s_u[TILE * Rpad];     // union: pc (ph0b/1), cols (ph2/3)
    __shared__ float s_py[TILE][P];
    __shared__ float s_px[TILE][P];
    __shared__ ushort_t s_mask[TILE][P];      // bf16

    ushort_t* s_patchh = (ushort_t*)s_patch32;
    float*    s_patchf = (float*)s_patch32;

    const int tilesPerImg = (Ho * Wo) / TILE;
    const int b    = blockIdx.x / tilesPerImg;
    const int tile = blockIdx.x % tilesPerImg;
    const int base = tile * TILE;             // TILE | Wo -> single output row
    const int tid  = threadIdx.x;
    const int wid  = tid >> 6, lane = tid & 63;
    const int lr   = lane & 15;               // fragment row / pixel column
    const int lk8  = (lane >> 4) * 8;         // fragment K offset (elements)

    const int oy0 = base / Wo;
    const int ox0 = base % Wo;
    const int iy0 = oy0 * STRIDE - PAD;
    const int ix0 = ox0 * STRIDE - PAD;

    const float* xb = x + (size_t)b * CIN * H * W;

    // ---- phase 0a: halo patch -> LDS ----
    if constexpr (PMODE == 2 || PMODE == 3) {
        for (int idx = tid; idx < PELN; idx += 256) {
            const int c   = idx / (PROWS * PCOLS);
            const int rem = idx % (PROWS * PCOLS);
            const int pr  = rem / PCOLS;
            const int pc_ = rem % PCOLS;
            const int iy = iy0 - 1 + pr, ix = ix0 - 1 + pc_;
            float v = 0.0f;
            if (iy >= 0 && iy < H && ix >= 0 && ix < W)
                v = xb[(size_t)c * H * W + iy * W + ix];
            if constexpr (PMODE == 2) s_patchf[idx] = v;
            else                      s_patchh[idx] = f2bf(v);
        }
        __syncthreads();
    }

    // ---- phase 0b: im2col expand -> s_u (thread<->rr, loop pix) ----
    for (int rr = tid; rr < Rpad; rr += 256) {
        if (rr < R) {
            const int c = rr / P, p = rr % P;
            const int ky = p / K, kx = p % K;
            if constexpr (PMODE == 2) {
                const float* srcrow =
                    &s_patchf[(c * PROWS + ky + 1) * PCOLS + kx + 1];
                #pragma unroll 4
                for (int pix = 0; pix < TILE; ++pix)
                    s_u[pix * Rpad + (rr ^ ((pix & 7) << 3))] =
                        f2bf(srcrow[pix * STRIDE]);
            } else if constexpr (PMODE == 3) {
                const ushort_t* srcrow =
                    &s_patchh[(c * PROWS + ky + 1) * PCOLS + kx + 1];
                #pragma unroll 4
                for (int pix = 0; pix < TILE; ++pix)
                    s_u[pix * Rpad + (rr ^ ((pix & 7) << 3))] =
                        srcrow[pix * STRIDE];
            } else {
                const int iy = iy0 + ky;
                const bool rowok = (iy >= 0 && iy < H);
                const float* xrow = xb + (size_t)c * H * W +
                                    (size_t)(rowok ? iy : 0) * W;
                #pragma unroll 4
                for (int pix = 0; pix < TILE; ++pix) {
                    const int ix = ix0 + pix * STRIDE + kx;
                    float v = 0.0f;
                    if (rowok && ix >= 0 && ix < W) v = xrow[ix];
                    s_u[pix * Rpad + (rr ^ ((pix & 7) << 3))] = f2bf(v);
                }
            }
        } else {
            #pragma unroll 4
            for (int pix = 0; pix < TILE; ++pix)
                s_u[pix * Rpad + (rr ^ ((pix & 7) << 3))] = 0;
        }
    }
    __syncthreads();

    // ---- phase 1: offset conv via MFMA; fused-coord epilogue ----
    {
        f32x4 acc1[MT1PW][NT] = {};
        for (int kt = 0; kt < KT; ++kt) {
            bfrag8 bfr[NT];
            #pragma unroll
            for (int nt = 0; nt < NT; ++nt)
                bfr[nt] = *(const bfrag8*)&s_u[(nt * 16 + lr) * Rpad +
                              ((kt * 32 + lk8) ^ ((lr & 7) << 3))];
            #pragma unroll
            for (int i = 0; i < MT1PW; ++i) {
                const int mt = wid + 4 * i;
                if (mt < MT1) {
                    const bfrag8 afr = *(const bfrag8*)&owpk[
                        (size_t)(mt * 16 + lr) * Rpad + kt * 32 + lk8];
                    #pragma unroll
                    for (int nt = 0; nt < NT; ++nt)
                        acc1[i][nt] = __builtin_amdgcn_mfma_f32_16x16x32_bf16(
                            afr, bfr[nt], acc1[i][nt], 0, 0, 0);
                }
            }
        }
        if (lr < LRLIM) {
            #pragma unroll
            for (int i = 0; i < MT1PW; ++i) {
                const int mt = wid + 4 * i;
                if (mt < MT1) {
                    #pragma unroll
                    for (int nt = 0; nt < NT; ++nt) {
                        const int pix = nt * 16 + lr;
                        #pragma unroll
                        for (int q = 0; q < 4; ++q) {
                            const int ch = mt * 16 + (lane >> 4) * 4 + q;
                            if (ch < P3) {
                                const float v = acc1[i][nt][q] + ob[ch];
                                if (ch < 2 * P) {
                                    const int p = ch >> 1;
                                    if (ch & 1)
                                        s_px[pix][p] = (float)(ix0 + pix * STRIDE
                                                               + p % K) + v;
                                    else
                                        s_py[pix][p] = (float)(iy0 + p / K) + v;
                                } else {
                                    s_mask[pix][ch - 2 * P] =
                                        f2bf(1.0f / (1.0f + __expf(-v)));
                                }
                            }
                        }
                    }
                }
            }
        }
    }
    __syncthreads();   // phase-1 s_u reads drained (lgkmcnt 0) -> reuse as cols

    // ---- phase 2: bilinear sample * mask -> s_u (coords shared
    //      across channels; one item = one (pix,p,changroup) tuple) ----
    {
        constexpr int ITEMS = TILE * P;
        constexpr int CG  = (ITEMS >= 256) ? 1 : (256 / ITEMS);  // chan groups
        constexpr int CPG = CIN / CG;                            // chans/group
        constexpr int PSZ = PROWS * PCOLS;
        const int HW = H * W;
        for (int it = tid; it < ITEMS * CG; it += 256) {
            int item, cg;
            if constexpr (CG == 1) { item = it; cg = 0; }
            else { item = it % ITEMS; cg = it / ITEMS; }
            const int p   = item % P;
            const int pix = item / P;
            const float py = s_py[pix][p];
            const float px = s_px[pix][p];
            const float mk = bf2f(s_mask[pix][p]);
            const float y0f = floorf(py), x0f = floorf(px);
            const float wy = py - y0f, wx = px - x0f;
            const int y0 = (int)y0f, x0 = (int)x0f;
            const int swz = (pix & 7) << 3;
            ushort_t* dst = &s_u[pix * Rpad];
            bool done = false;
            if constexpr (PMODE == 2) {
                const int pyr = y0 - (iy0 - 1);
                const int pxr = x0 - (ix0 - 1);
                if (pyr >= 0 && pyr < PROWS - 1 && pxr >= 0 && pxr < PCOLS - 1) {
                    const float* pp = &s_patchf[(size_t)(cg * CPG) * PSZ
                                                + pyr * PCOLS + pxr];
                    int c = cg * CPG;
                    #pragma unroll
                    for (int ci = 0; ci < CPG; ++ci, ++c) {
                        const float v00 = pp[0], v01 = pp[1];
                        const float v10 = pp[PCOLS], v11 = pp[PCOLS + 1];
                        const float top = v00 + wx * (v01 - v00);
                        const float bot = v10 + wx * (v11 - v10);
                        const float acc = top + wy * (bot - top);
                        dst[(c * P + p) ^ swz] = f2bf(acc * mk);
                        pp += PSZ;
                    }
                    done = true;
                }
            } else if constexpr (PMODE == 3) {
                const int pyr = y0 - (iy0 - 1);
                const int pxr = x0 - (ix0 - 1);
                if (pyr >= 0 && pyr < PROWS - 1 && pxr >= 0 && pxr < PCOLS - 1) {
                    const ushort_t* pp = &s_patchh[(size_t)(cg * CPG) * PSZ
                                                   + pyr * PCOLS + pxr];
                    int c = cg * CPG;
                    #pragma unroll 4
                    for (int ci = 0; ci < CPG; ++ci, ++c) {
                        const float v00 = bf2f(pp[0]), v01 = bf2f(pp[1]);
                        const float v10 = bf2f(pp[PCOLS]), v11 = bf2f(pp[PCOLS + 1]);
                        const float top = v00 + wx * (v01 - v00);
                        const float bot = v10 + wx * (v11 - v10);
                        const float acc = top + wy * (bot - top);
                        dst[(c * P + p) ^ swz] = f2bf(acc * mk);
                        pp += PSZ;
                    }
                    done = true;
                }
            }
            if (!done) {
                if (y0 >= 0 && y0 < H - 1 && x0 >= 0 && x0 < W - 1) {
                    const float* pr = xb + (size_t)(cg * CPG) * HW
                                         + (size_t)y0 * W + x0;
                    int c = cg * CPG;
                    for (int ci = 0; ci < CPG; ++ci, ++c) {
                        const float v00 = pr[0], v01 = pr[1];
                        const float v10 = pr[W], v11 = pr[W + 1];
                        const float top = v00 + wx * (v01 - v00);
                        const float bot = v10 + wx * (v11 - v10);
                        const float acc = top + wy * (bot - top);
                        dst[(c * P + p) ^ swz] = f2bf(acc * mk);
                        pr += HW;
                    }
                } else {
                    const bool y0ok = (y0 >= 0 && y0 < H);
                    const bool y1ok = (y0 + 1 >= 0 && y0 + 1 < H);
                    const bool x0ok = (x0 >= 0 && x0 < W);
                    const bool x1ok = (x0 + 1 >= 0 && x0 + 1 < W);
                    const float w00 = (1.0f - wy) * (1.0f - wx);
                    const float w01 = (1.0f - wy) * wx;
                    const float w10 = wy * (1.0f - wx);
                    const float w11 = wy * wx;
                    const float* xc = xb + (size_t)(cg * CPG) * HW;
                    int c = cg * CPG;
                    for (int ci = 0; ci < CPG; ++ci, ++c) {
                        float acc = 0.0f;
                        if (y0ok) {
                            const float* pr = xc + (size_t)y0 * W + x0;
                            if (x0ok) acc += pr[0] * w00;
                            if (x1ok) acc += pr[1] * w01;
                        }
                        if (y1ok) {
                            const float* pr = xc + (size_t)(y0 + 1) * W + x0;
                            if (x0ok) acc += pr[0] * w10;
                            if (x1ok) acc += pr[1] * w11;
                        }
                        dst[(c * P + p) ^ swz] = f2bf(acc * mk);
                        xc += HW;
                    }
                }
            }
        }
        // zero-fill padded K region
        if constexpr (Rpad != R) {
            for (int idx = tid; idx < (Rpad - R) * TILE; idx += 256) {
                const int r   = R + idx / TILE;
                const int pix = idx % TILE;
                s_u[pix * Rpad + (r ^ ((pix & 7) << 3))] = 0;
            }
        }
    }
    __syncthreads();

    // ---- phase 3: main conv via MFMA ----
    {
        f32x4 acc3[MT3PW][NT] = {};
        for (int kt = 0; kt < KT; ++kt) {
            bfrag8 bfr[NT];
            #pragma unroll
            for (int nt = 0; nt < NT; ++nt)
                bfr[nt] = *(const bfrag8*)&s_u[(nt * 16 + lr) * Rpad +
                              ((kt * 32 + lk8) ^ ((lr & 7) << 3))];
            #pragma unroll
            for (int i = 0; i < MT3PW; ++i) {
                const int mt = wid + 4 * i;
                if (mt < MT3) {
                    const bfrag8 afr = *(const bfrag8*)&wpk[
                        (size_t)(mt * 16 + lr) * Rpad + kt * 32 + lk8];
                    #pragma unroll
                    for (int nt = 0; nt < NT; ++nt)
                        acc3[i][nt] = __builtin_amdgcn_mfma_f32_16x16x32_bf16(
                            afr, bfr[nt], acc3[i][nt], 0, 0, 0);
                }
            }
        }
        if (lr < LRLIM) {
            #pragma unroll
            for (int i = 0; i < MT3PW; ++i) {
                const int mt = wid + 4 * i;
                if (mt < MT3) {
                    #pragma unroll
                    for (int nt = 0; nt < NT; ++nt) {
                        #pragma unroll
                        for (int q = 0; q < 4; ++q) {
                            const int ch = mt * 16 + (lane >> 4) * 4 + q;
                            out[(((size_t)b * COUT + ch) * Ho + oy0) * Wo
                                + ox0 + nt * 16 + lr] = acc3[i][nt][q] + bias[ch];
                        }
                    }
                }
            }
        }
    }
}

// ================= instance norm (one block per (b,c) plane) =================
// float4-vectorized; BS templated (1024 thr for large planes: more waves/CU
// for HBM latency hiding -- the large-plane INs run at 1-2 blocks/CU).
template<int BS>
__global__ __launch_bounds__(BS) void in_relu_kernel(float* __restrict__ data,
                                                     int HW, int relu)
{
    float* plane = data + (size_t)blockIdx.x * HW;
    const int tid = threadIdx.x;
    float s = 0.0f, s2 = 0.0f;
    for (int i = tid * 4; i < HW; i += BS * 4) {
        const float4 v = *(const float4*)&plane[i];
        s  += v.x + v.y + v.z + v.w;
        s2 += v.x * v.x + v.y * v.y + v.z * v.z + v.w * v.w;
    }
    __shared__ float red0[BS];
    __shared__ float red1[BS];
    red0[tid] = s; red1[tid] = s2;
    __syncthreads();
    for (int off = BS / 2; off > 0; off >>= 1) {
        if (tid < off) { red0[tid] += red0[tid + off]; red1[tid] += red1[tid + off]; }
        __syncthreads();
    }
    const float mean = red0[0] / (float)HW;
    float var = red1[0] / (float)HW - mean * mean;
    var = fmaxf(var, 0.0f);
    const float rstd = rsqrtf(var + EPS);
    for (int i = tid * 4; i < HW; i += BS * 4) {
        float4 v = *(const float4*)&plane[i];
        v.x = (v.x - mean) * rstd; v.y = (v.y - mean) * rstd;
        v.z = (v.z - mean) * rstd; v.w = (v.w - mean) * rstd;
        if (relu) {
            v.x = fmaxf(v.x, 0.0f); v.y = fmaxf(v.y, 0.0f);
            v.z = fmaxf(v.z, 0.0f); v.w = fmaxf(v.w, 0.0f);
        }
        *(float4*)&plane[i] = v;
    }
}

// h += 0.1 * instance_norm(r)   (in-place on workspace h)
__global__ __launch_bounds__(256) void in_resadd_kernel(float* __restrict__ h,
                                                        const float* __restrict__ r,
                                                        int HW)
{
    const float* plane = r + (size_t)blockIdx.x * HW;
    float* hp = h + (size_t)blockIdx.x * HW;
    const int tid = threadIdx.x;
    float s = 0.0f, s2 = 0.0f;
    for (int i = tid * 4; i < HW; i += 1024) {
        const float4 v = *(const float4*)&plane[i];
        s  += v.x + v.y + v.z + v.w;
        s2 += v.x * v.x + v.y * v.y + v.z * v.z + v.w * v.w;
    }
    __shared__ float red0[256];
    __shared__ float red1[256];
    red0[tid] = s; red1[tid] = s2;
    __syncthreads();
    for (int off = 128; off > 0; off >>= 1) {
        if (tid < off) { red0[tid] += red0[tid + off]; red1[tid] += red1[tid + off]; }
        __syncthreads();
    }
    const float mean = red0[0] / (float)HW;
    float var = red1[0] / (float)HW - mean * mean;
    var = fmaxf(var, 0.0f);
    const float rstd = rsqrtf(var + EPS);
    for (int i = tid * 4; i < HW; i += 1024) {
        const float4 v = *(const float4*)&plane[i];
        float4 o = *(const float4*)&hp[i];
        o.x += 0.1f * ((v.x - mean) * rstd);
        o.y += 0.1f * ((v.y - mean) * rstd);
        o.z += 0.1f * ((v.z - mean) * rstd);
        o.w += 0.1f * ((v.w - mean) * rstd);
        *(float4*)&hp[i] = o;
    }
}

// dst = h + 0.1 * instance_norm(r)   (d_out written exactly once at the end)
__global__ __launch_bounds__(256) void in_resadd_out_kernel(
    float* __restrict__ dst, const float* __restrict__ h,
    const float* __restrict__ r, int HW)
{
    const float* plane = r + (size_t)blockIdx.x * HW;
    const float* hp = h + (size_t)blockIdx.x * HW;
    float* dp = dst + (size_t)blockIdx.x * HW;
    const int tid = threadIdx.x;
    float s = 0.0f, s2 = 0.0f;
    for (int i = tid * 4; i < HW; i += 1024) {
        const float4 v = *(const float4*)&plane[i];
        s  += v.x + v.y + v.z + v.w;
        s2 += v.x * v.x + v.y * v.y + v.z * v.z + v.w * v.w;
    }
    __shared__ float red0[256];
    __shared__ float red1[256];
    red0[tid] = s; red1[tid] = s2;
    __syncthreads();
    for (int off = 128; off > 0; off >>= 1) {
        if (tid < off) { red0[tid] += red0[tid + off]; red1[tid] += red1[tid + off]; }
        __syncthreads();
    }
    const float mean = red0[0] / (float)HW;
    float var = red1[0] / (float)HW - mean * mean;
    var = fmaxf(var, 0.0f);
    const float rstd = rsqrtf(var + EPS);
    for (int i = tid * 4; i < HW; i += 1024) {
        const float4 v = *(const float4*)&plane[i];
        const float4 o = *(const float4*)&hp[i];
        float4 d;
        d.x = o.x + 0.1f * ((v.x - mean) * rstd);
        d.y = o.y + 0.1f * ((v.y - mean) * rstd);
        d.z = o.z + 0.1f * ((v.z - mean) * rstd);
        d.w = o.w + 0.1f * ((v.w - mean) * rstd);
        *(float4*)&dp[i] = d;
    }
}

// ================= res-conv path: tiled im2col + bf16 MFMA GEMM =============
__global__ __launch_bounds__(256) void im2col_tiled_kernel(
    const float* __restrict__ in, ushort_t* __restrict__ cols)
{
    // grid = 8 b * 32 y * 4 cgroups = 1024
    const int bid = blockIdx.x;
    const int cg = bid & 3;
    const int y  = (bid >> 2) & 31;
    const int b  = bid >> 7;
    const int c0 = cg * 64;
    const int tid = threadIdx.x;

    __shared__ float s_p[64 * 3 * 34];   // [c][row][x], 26.1 KB

    // phase A: stage input slab (zero-padded)
    for (int idx = tid; idx < 64 * 3 * 34; idx += 256) {
        const int c   = idx / 102;
        const int rem = idx % 102;
        const int r   = rem / 34;
        const int xx  = rem % 34;
        const int yy = y + r - 1;
        const int gx = xx - 1;
        float v = 0.0f;
        if (yy >= 0 && yy < 32 && gx >= 0 && gx < 32)
            v = in[(((size_t)b * 256 + c0 + c) * 32 + yy) * 32 + gx];
        s_p[idx] = v;
    }
    __syncthreads();

    // phase B: 32 xout * 16 c-quads = 512 items
    for (int it = tid; it < 512; it += 256) {
        const int xout = it >> 4;
        const int cq   = (it & 15) * 4;          // local c, multiple of 4
        const int n = b * 1024 + y * 32 + xout;
        ushort_t* oc = cols + (size_t)n * 2304 + (size_t)(c0 + cq) * 9;
        ushort_t tmp[36];
        #pragma unroll
        for (int ci = 0; ci < 4; ++ci)
            #pragma unroll
            for (int ky = 0; ky < 3; ++ky)
                #pragma unroll
                for (int kx = 0; kx < 3; ++kx)
                    tmp[ci * 9 + ky * 3 + kx] =
                        f2bf(s_p[(cq + ci) * 102 + ky * 34 + xout + kx]);
        #pragma unroll
        for (int i2 = 0; i2 < 9; ++i2) {
            unsigned long long w =
                  (unsigned long long)tmp[4 * i2]
                | ((unsigned long long)tmp[4 * i2 + 1] << 16)
                | ((unsigned long long)tmp[4 * i2 + 2] << 32)
                | ((unsigned long long)tmp[4 * i2 + 3] << 48);
            *((unsigned long long*)oc + i2) = w;   // 8B-aligned: (c0+cq)%4==0
        }
    }
}

__global__ __launch_bounds__(256) void f32_to_bf16_kernel(
    const float* __restrict__ in, ushort_t* __restrict__ out, int n)
{
    const int i = blockIdx.x * 256 + threadIdx.x;
    if (i < n) out[i] = f2bf(in[i]);
}

// C[m][n] = bias[m] + sum_k A[m][k]*Bt[n][k]; A,Bt bf16 K-contiguous.
// BM=64, BN=128, BK=64; 512 threads = 8 waves (2x4 of 32x32 each).
__global__ __launch_bounds__(512) void gemm_bf16_kernel(
    const ushort_t* __restrict__ A,   // [256][2304]
    const ushort_t* __restrict__ Bt,  // [8192][2304]
    const float* __restrict__ bias,   // [256]
    float* __restrict__ C)            // [8][256][1024], n=b*1024+pix
{
    constexpr int Kt = 2304;
    __shared__ ushort_t sA[64][72];
    __shared__ ushort_t sB[128][72];

    const int m0 = blockIdx.x * 64;
    const int n0 = blockIdx.y * 128;
    const int tid  = threadIdx.x;
    const int wid  = tid >> 6, lane = tid & 63;   // wid 0..7
    const int wm = wid & 1, wn = wid >> 1;        // 2 x 4 wave grid
    const int lr = lane & 15, lk = (lane >> 4) * 8;

    const int srow = tid >> 3, sseg = (tid & 7) * 8;   // srow 0..63
    const ushort_t* ap  = A  + (size_t)(m0 + srow) * Kt + sseg;
    const ushort_t* bp0 = Bt + (size_t)(n0 + srow) * Kt + sseg;
    const ushort_t* bp1 = Bt + (size_t)(n0 + 64 + srow) * Kt + sseg;

    f32x4 acc[2][2] = {};

    for (int k0 = 0; k0 < Kt; k0 += 64) {
        __syncthreads();                       // prev iteration's reads done
        *(int4*)&sA[srow][sseg]      = *(const int4*)(ap + k0);
        *(int4*)&sB[srow][sseg]      = *(const int4*)(bp0 + k0);
        *(int4*)&sB[64 + srow][sseg] = *(const int4*)(bp1 + k0);
        __syncthreads();                       // staging visible

        #pragma unroll
        for (int ks = 0; ks < 2; ++ks) {
            bfrag8 af[2], bf[2];
            #pragma unroll
            for (int mi = 0; mi < 2; ++mi)
                af[mi] = *(const bfrag8*)&sA[wm * 32 + mi * 16 + lr][ks * 32 + lk];
            #pragma unroll
            for (int nj = 0; nj < 2; ++nj)
                bf[nj] = *(const bfrag8*)&sB[wn * 32 + nj * 16 + lr][ks * 32 + lk];
            #pragma unroll
            for (int mi = 0; mi < 2; ++mi)
                #pragma unroll
                for (int nj = 0; nj < 2; ++nj)
                    acc[mi][nj] = __builtin_amdgcn_mfma_f32_16x16x32_bf16(
                        af[mi], bf[nj], acc[mi][nj], 0, 0, 0);
        }
    }

    #pragma unroll
    for (int mi = 0; mi < 2; ++mi) {
        #pragma unroll
        for (int nj = 0; nj < 2; ++nj) {
            const int n = n0 + wn * 32 + nj * 16 + lr;
            const int b = n >> 10, pix = n & 1023;
            #pragma unroll
            for (int r = 0; r < 4; ++r) {
                const int m = m0 + wm * 32 + mi * 16 + (lane >> 4) * 4 + r;
                C[(((size_t)b * 256 + m) << 10) + pix] = acc[mi][nj][r] + bias[m];
            }
        }
    }
}

// ================= launch =================
extern "C" void kernel_launch(void* const* d_in, const int* in_sizes, int n_in,
                              void* d_out, int out_size, void* d_ws, size_t ws_size,
                              hipStream_t stream)
{
    const float* x    = (const float*)d_in[0];
    const float* d1w  = (const float*)d_in[1];
    const float* d1b  = (const float*)d_in[2];
    const float* d1ow = (const float*)d_in[3];
    const float* d1ob = (const float*)d_in[4];
    const float* d2w  = (const float*)d_in[5];
    const float* d2b  = (const float*)d_in[6];
    const float* d2ow = (const float*)d_in[7];
    const float* d2ob = (const float*)d_in[8];
    const float* d3w  = (const float*)d_in[9];
    const float* d3b  = (const float*)d_in[10];
    const float* d3ow = (const float*)d_in[11];
    const float* d3ob = (const float*)d_in[12];
    const float* d4w  = (const float*)d_in[13];
    const float* d4b  = (const float*)d_in[14];
    const float* d4ow = (const float*)d_in[15];
    const float* d4ob = (const float*)d_in[16];
    const float* resw = (const float*)d_in[17];
    const float* resb = (const float*)d_in[18];

    float* A   = (float*)d_ws;          // [0 .. 16,777,216) floats
    float* Bb  = A + 16777216;          // [16,777,216 .. 25,165,824) floats
    float* out = (float*)d_out;         // 8x256x32x32, write-once at the end

    // dcn weight packs live in d_out's bytes (free scratch: d_out is fully
    // overwritten by the final kernel). 897,024 ushorts = 1.79 MB < 8.4 MB.
    ushort_t* pk = (ushort_t*)d_out;
    ushort_t* ow1 = pk;                 // 160*192
    ushort_t* w1  = ow1 + 160 * 192;    // 32*192
    ushort_t* ow2 = w1  + 32 * 192;     // 48*512
    ushort_t* w2  = ow2 + 48 * 512;     // 64*512
    ushort_t* ow3 = w2  + 64 * 512;     // 48*1024
    ushort_t* w3  = ow3 + 48 * 1024;    // 128*1024
    ushort_t* ow4 = w3  + 128 * 1024;   // 48*2048
    ushort_t* w4  = ow4 + 48 * 2048;    // 256*2048

    // workspace sub-regions for the res phase:
    float* r    = A;                                   // [0 .. 2,097,152)
    float* r2   = A + 2097152;
    ushort_t* cols = (ushort_t*)(A + 4194304);         // 8192*2304 bf16
    ushort_t* wbf  = (ushort_t*)Bb;                    // 4*589,824 bf16
    float* H4   = Bb + 4194304;                        // 2,097,152 floats

    const int B = 8;

    // ---- weight prepack (bf16, K-padded) ----
    pack_w_kernel<<<(160 * 192 + 255) / 256, 256, 0, stream>>>(d1ow, ow1, 147, 147, 160, 192);
    pack_w_kernel<<<(32 * 192 + 255) / 256, 256, 0, stream>>>(d1w, w1, 32, 147, 32, 192);
    pack_w_kernel<<<(48 * 512 + 255) / 256, 256, 0, stream>>>(d2ow, ow2, 48, 512, 48, 512);
    pack_w_kernel<<<(64 * 512 + 255) / 256, 256, 0, stream>>>(d2w, w2, 64, 512, 64, 512);
    pack_w_kernel<<<(48 * 1024 + 255) / 256, 256, 0, stream>>>(d3ow, ow3, 48, 1024, 48, 1024);
    pack_w_kernel<<<(128 * 1024 + 255) / 256, 256, 0, stream>>>(d3w, w3, 128, 1024, 128, 1024);
    pack_w_kernel<<<(48 * 2048 + 255) / 256, 256, 0, stream>>>(d4ow, ow4, 48, 2048, 48, 2048);
    pack_w_kernel<<<(256 * 2048 + 255) / 256, 256, 0, stream>>>(d4w, w4, 256, 2048, 256, 2048);

    // dcn1: 3->32, K=7 s=1 p=3; 256x256  (NT=2, fp32 halo patch + bf16 mask)
    dcn_mfma_kernel<3, 32, 7, 1, 3, 32, 2><<<B * (256 * 256 / 32), 256, 0, stream>>>(
        x, 256, 256, w1, d1b, ow1, d1ob, A, 256, 256);
    in_relu_kernel<1024><<<B * 32, 1024, 0, stream>>>(A, 65536, 1);

    // dcn2: 32->64, K=4 s=2 p=1; 256 -> 128  (bf16 halo patch; ~32.8 KB)
    dcn_mfma_kernel<32, 64, 4, 2, 1, 16, 3><<<B * (128 * 128 / 16), 256, 0, stream>>>(
        A, 256, 256, w2, d2b, ow2, d2ob, Bb, 128, 128);
    in_relu_kernel<1024><<<B * 64, 1024, 0, stream>>>(Bb, 16384, 1);

    // dcn3: 64->128, K=4 s=2 p=1; 128 -> 64  (bf16 halo patch, TILE=8; ~33 KB)
    dcn_mfma_kernel<64, 128, 4, 2, 1, 8, 3><<<B * (64 * 64 / 8), 256, 0, stream>>>(
        Bb, 128, 128, w3, d3b, ow3, d3ob, A, 64, 64);
    in_relu_kernel<1024><<<B * 128, 1024, 0, stream>>>(A, 4096, 1);

    // dcn4: 128->256, K=4 s=2 p=1; 64 -> 32 -> H4  (patchless TILE=8; ~34 KB)
    dcn_mfma_kernel<128, 256, 4, 2, 1, 8, 0><<<B * (32 * 32 / 8), 256, 0, stream>>>(
        A, 64, 64, w4, d4b, ow4, d4ob, H4, 32, 32);
    in_relu_kernel<256><<<B * 256, 256, 0, stream>>>(H4, 1024, 1);

    // --- residual blocks via bf16 MFMA GEMM ---
    f32_to_bf16_kernel<<<(4 * 589824 + 255) / 256, 256, 0, stream>>>(
        resw, wbf, 4 * 589824);

    dim3 ggrid(4, 64);
    // i = 0 : h (H4) updated in place
    im2col_tiled_kernel<<<1024, 256, 0, stream>>>(H4, cols);
    gemm_bf16_kernel<<<ggrid, 512, 0, stream>>>(
        wbf + (size_t)0 * 589824, cols, resb + 0 * 256, r);
    in_relu_kernel<256><<<B * 256, 256, 0, stream>>>(r, 1024, 1);
    im2col_tiled_kernel<<<1024, 256, 0, stream>>>(r, cols);
    gemm_bf16_kernel<<<ggrid, 512, 0, stream>>>(
        wbf + (size_t)1 * 589824, cols, resb + 1 * 256, r2);
    in_resadd_kernel<<<B * 256, 256, 0, stream>>>(H4, r2, 1024);

    // i = 1 : final result goes straight to d_out (write-once, covers packs)
    im2col_tiled_kernel<<<1024, 256, 0, stream>>>(H4, cols);
    gemm_bf16_kernel<<<ggrid, 512, 0, stream>>>(
        wbf + (size_t)2 * 589824, cols, resb + 2 * 256, r);
    in_relu_kernel<256><<<B * 256, 256, 0, stream>>>(r, 1024, 1);
    im2col_tiled_kernel<<<1024, 256, 0, stream>>>(r, cols);
    gemm_bf16_kernel<<<ggrid, 512, 0, stream>>>(
        wbf + (size_t)3 * 589824, cols, resb + 3 * 256, r2);
    in_resadd_out_kernel<<<B * 256, 256, 0, stream>>>(out, H4, r2, 1024);
}

// Round 20
// 1217.525 us; speedup vs baseline: 1.0867x; 1.0106x over previous
//
#include <hip/hip_runtime.h>
#include <hip/hip_bf16.h>
#include <math.h>

#define EPS 1e-5f

typedef short bfrag8 __attribute__((ext_vector_type(8)));   // 8 bf16 (4 VGPRs)
typedef float f32x4 __attribute__((ext_vector_type(4)));
typedef unsigned short ushort_t;

__device__ inline ushort_t f2bf(float f) {
    __hip_bfloat16 h = __float2bfloat16(f);
    return *reinterpret_cast<ushort_t*>(&h);
}
__device__ inline float bf2f(ushort_t u) {
    unsigned int v = ((unsigned int)u) << 16;
    float f;
    __builtin_memcpy(&f, &v, 4);
    return f;
}

// ====== weight prepack: fp32 [M][R] -> bf16 [Mpad][Rpad] (zero-padded) ======
__global__ __launch_bounds__(256) void pack_w_kernel(
    const float* __restrict__ src, ushort_t* __restrict__ dst,
    int M, int R, int Mpad, int Rpad)
{
    const int idx = blockIdx.x * 256 + threadIdx.x;
    if (idx >= Mpad * Rpad) return;
    const int m = idx / Rpad, r = idx % Rpad;
    float v = 0.0f;
    if (m < M && r < R) v = src[(size_t)m * R + r];
    dst[idx] = f2bf(v);
}

// ================= fused modulated-deformable-conv stage (MFMA) =============
// One block (256 thr = 4 waves) per TILE consecutive output pixels (one row,
// NT = TILE/16 MFMA n-tiles, LRLIM = min(TILE,16)).
// PMODE 0: global im2col + global bilinear                     (dcn4)
// PMODE 2: fp32 halo patch, phase0b + LDS phase2 bilinear     (dcn1)
// PMODE 3: bf16 halo patch, phase0b + LDS phase2 bilinear     (dcn2, dcn3)
// Halo = 1 px; samples outside the patch fall back to exact global path.
// s_u is a UNION: im2col operand for phase1, then cols for phase3; the
// __syncthreads at each boundary implies lgkmcnt(0) -> race-free.
template<int CIN, int COUT, int K, int STRIDE, int PAD, int TILE, int PMODE>
__global__ __launch_bounds__(256, 4) void dcn_mfma_kernel(
    const float* __restrict__ x, int H, int W,
    const ushort_t* __restrict__ wpk,   // [COUT][Rpad] bf16
    const float* __restrict__ bias,     // [COUT]
    const ushort_t* __restrict__ owpk,  // [M1pad][Rpad] bf16
    const float* __restrict__ ob,       // [3P]
    float* __restrict__ out, int Ho, int Wo)
{
    constexpr int P     = K * K;
    constexpr int P3    = 3 * P;
    constexpr int R     = CIN * P;
    constexpr int Rpad  = (R + 63) & ~63;
    constexpr int KT    = Rpad / 32;
    constexpr int NT    = (TILE + 15) / 16;   // MFMA n-tiles
    constexpr int MT1   = (P3 + 15) / 16;     // m-tiles, offset conv
    constexpr int MT1PW = (MT1 + 3) / 4;
    constexpr int MT3   = COUT / 16;          // m-tiles, main conv
    constexpr int MT3PW = (MT3 + 3) / 4;
    constexpr int COLS  = (TILE - 1) * STRIDE + K;
    constexpr int PROWS = K + 2;              // halo rows (modes 2/3)
    constexpr int PCOLS = COLS + 2;           // halo cols (modes 2/3)
    constexpr int PELN  = CIN * PROWS * PCOLS;
    constexpr int P32   = (PMODE == 2) ? PELN : (PMODE == 3) ? (PELN + 1) / 2 : 1;
    constexpr int LRLIM = (TILE < 16) ? TILE : 16;

    __shared__ unsigned int s_patch32[P32];
    __shared__ ushort_t s_u[TILE * Rpad];     // union: pc (ph0b/1), cols (ph2/3)
    __shared__ float s_py[TILE][P];
    __shared__ float s_px[TILE][P];
    __shared__ ushort_t s_mask[TILE][P];      // bf16

    ushort_t* s_patchh = (ushort_t*)s_patch32;
    float*    s_patchf = (float*)s_patch32;

    const int tilesPerImg = (Ho * Wo) / TILE;
    const int b    = blockIdx.x / tilesPerImg;
    const int tile = blockIdx.x % tilesPerImg;
    const int base = tile * TILE;             // TILE | Wo -> single output row
    const int tid  = threadIdx.x;
    const int wid  = tid >> 6, lane = tid & 63;
    const int lr   = lane & 15;               // fragment row / pixel column
    const int lk8  = (lane >> 4) * 8;         // fragment K offset (elements)

    const int oy0 = base / Wo;
    const int ox0 = base % Wo;
    const int iy0 = oy0 * STRIDE - PAD;
    const int ix0 = ox0 * STRIDE - PAD;

    const float* xb = x + (size_t)b * CIN * H * W;

    // ---- phase 0a: halo patch -> LDS ----
    if constexpr (PMODE == 2 || PMODE == 3) {
        for (int idx = tid; idx < PELN; idx += 256) {
            const int c   = idx / (PROWS * PCOLS);
            const int rem = idx % (PROWS * PCOLS);
            const int pr  = rem / PCOLS;
            const int pc_ = rem % PCOLS;
            const int iy = iy0 - 1 + pr, ix = ix0 - 1 + pc_;
            float v = 0.0f;
            if (iy >= 0 && iy < H && ix >= 0 && ix < W)
                v = xb[(size_t)c * H * W + iy * W + ix];
            if constexpr (PMODE == 2) s_patchf[idx] = v;
            else                      s_patchh[idx] = f2bf(v);
        }
        __syncthreads();
    }

    // ---- phase 0b: im2col expand -> s_u (thread<->rr, loop pix) ----
    for (int rr = tid; rr < Rpad; rr += 256) {
        if (rr < R) {
            const int c = rr / P, p = rr % P;
            const int ky = p / K, kx = p % K;
            if constexpr (PMODE == 2) {
                const float* srcrow =
                    &s_patchf[(c * PROWS + ky + 1) * PCOLS + kx + 1];
                #pragma unroll 4
                for (int pix = 0; pix < TILE; ++pix)
                    s_u[pix * Rpad + (rr ^ ((pix & 7) << 3))] =
                        f2bf(srcrow[pix * STRIDE]);
            } else if constexpr (PMODE == 3) {
                const ushort_t* srcrow =
                    &s_patchh[(c * PROWS + ky + 1) * PCOLS + kx + 1];
                #pragma unroll 4
                for (int pix = 0; pix < TILE; ++pix)
                    s_u[pix * Rpad + (rr ^ ((pix & 7) << 3))] =
                        srcrow[pix * STRIDE];
            } else {
                const int iy = iy0 + ky;
                const bool rowok = (iy >= 0 && iy < H);
                const float* xrow = xb + (size_t)c * H * W +
                                    (size_t)(rowok ? iy : 0) * W;
                #pragma unroll 4
                for (int pix = 0; pix < TILE; ++pix) {
                    const int ix = ix0 + pix * STRIDE + kx;
                    float v = 0.0f;
                    if (rowok && ix >= 0 && ix < W) v = xrow[ix];
                    s_u[pix * Rpad + (rr ^ ((pix & 7) << 3))] = f2bf(v);
                }
            }
        } else {
            #pragma unroll 4
            for (int pix = 0; pix < TILE; ++pix)
                s_u[pix * Rpad + (rr ^ ((pix & 7) << 3))] = 0;
        }
    }
    __syncthreads();

    // ---- phase 1: offset conv via MFMA; fused-coord epilogue ----
    {
        f32x4 acc1[MT1PW][NT] = {};
        for (int kt = 0; kt < KT; ++kt) {
            bfrag8 bfr[NT];
            #pragma unroll
            for (int nt = 0; nt < NT; ++nt)
                bfr[nt] = *(const bfrag8*)&s_u[(nt * 16 + lr) * Rpad +
                              ((kt * 32 + lk8) ^ ((lr & 7) << 3))];
            #pragma unroll
            for (int i = 0; i < MT1PW; ++i) {
                const int mt = wid + 4 * i;
                if (mt < MT1) {
                    const bfrag8 afr = *(const bfrag8*)&owpk[
                        (size_t)(mt * 16 + lr) * Rpad + kt * 32 + lk8];
                    #pragma unroll
                    for (int nt = 0; nt < NT; ++nt)
                        acc1[i][nt] = __builtin_amdgcn_mfma_f32_16x16x32_bf16(
                            afr, bfr[nt], acc1[i][nt], 0, 0, 0);
                }
            }
        }
        if (lr < LRLIM) {
            #pragma unroll
            for (int i = 0; i < MT1PW; ++i) {
                const int mt = wid + 4 * i;
                if (mt < MT1) {
                    #pragma unroll
                    for (int nt = 0; nt < NT; ++nt) {
                        const int pix = nt * 16 + lr;
                        #pragma unroll
                        for (int q = 0; q < 4; ++q) {
                            const int ch = mt * 16 + (lane >> 4) * 4 + q;
                            if (ch < P3) {
                                const float v = acc1[i][nt][q] + ob[ch];
                                if (ch < 2 * P) {
                                    const int p = ch >> 1;
                                    if (ch & 1)
                                        s_px[pix][p] = (float)(ix0 + pix * STRIDE
                                                               + p % K) + v;
                                    else
                                        s_py[pix][p] = (float)(iy0 + p / K) + v;
                                } else {
                                    s_mask[pix][ch - 2 * P] =
                                        f2bf(1.0f / (1.0f + __expf(-v)));
                                }
                            }
                        }
                    }
                }
            }
        }
    }
    __syncthreads();   // phase-1 s_u reads drained (lgkmcnt 0) -> reuse as cols

    // ---- phase 2: bilinear sample * mask -> s_u (coords shared
    //      across channels; one item = one (pix,p,changroup) tuple) ----
    {
        constexpr int ITEMS = TILE * P;
        constexpr int CG  = (ITEMS >= 256) ? 1 : (256 / ITEMS);  // chan groups
        constexpr int CPG = CIN / CG;                            // chans/group
        constexpr int PSZ = PROWS * PCOLS;
        const int HW = H * W;
        for (int it = tid; it < ITEMS * CG; it += 256) {
            int item, cg;
            if constexpr (CG == 1) { item = it; cg = 0; }
            else { item = it % ITEMS; cg = it / ITEMS; }
            const int p   = item % P;
            const int pix = item / P;
            const float py = s_py[pix][p];
            const float px = s_px[pix][p];
            const float mk = bf2f(s_mask[pix][p]);
            const float y0f = floorf(py), x0f = floorf(px);
            const float wy = py - y0f, wx = px - x0f;
            const int y0 = (int)y0f, x0 = (int)x0f;
            const int swz = (pix & 7) << 3;
            ushort_t* dst = &s_u[pix * Rpad];
            bool done = false;
            if constexpr (PMODE == 2) {
                const int pyr = y0 - (iy0 - 1);
                const int pxr = x0 - (ix0 - 1);
                if (pyr >= 0 && pyr < PROWS - 1 && pxr >= 0 && pxr < PCOLS - 1) {
                    const float* pp = &s_patchf[(size_t)(cg * CPG) * PSZ
                                                + pyr * PCOLS + pxr];
                    int c = cg * CPG;
                    #pragma unroll
                    for (int ci = 0; ci < CPG; ++ci, ++c) {
                        const float v00 = pp[0], v01 = pp[1];
                        const float v10 = pp[PCOLS], v11 = pp[PCOLS + 1];
                        const float top = v00 + wx * (v01 - v00);
                        const float bot = v10 + wx * (v11 - v10);
                        const float acc = top + wy * (bot - top);
                        dst[(c * P + p) ^ swz] = f2bf(acc * mk);
                        pp += PSZ;
                    }
                    done = true;
                }
            } else if constexpr (PMODE == 3) {
                const int pyr = y0 - (iy0 - 1);
                const int pxr = x0 - (ix0 - 1);
                if (pyr >= 0 && pyr < PROWS - 1 && pxr >= 0 && pxr < PCOLS - 1) {
                    const ushort_t* pp = &s_patchh[(size_t)(cg * CPG) * PSZ
                                                   + pyr * PCOLS + pxr];
                    int c = cg * CPG;
                    #pragma unroll 4
                    for (int ci = 0; ci < CPG; ++ci, ++c) {
                        const float v00 = bf2f(pp[0]), v01 = bf2f(pp[1]);
                        const float v10 = bf2f(pp[PCOLS]), v11 = bf2f(pp[PCOLS + 1]);
                        const float top = v00 + wx * (v01 - v00);
                        const float bot = v10 + wx * (v11 - v10);
                        const float acc = top + wy * (bot - top);
                        dst[(c * P + p) ^ swz] = f2bf(acc * mk);
                        pp += PSZ;
                    }
                    done = true;
                }
            }
            if (!done) {
                if (y0 >= 0 && y0 < H - 1 && x0 >= 0 && x0 < W - 1) {
                    const float* pr = xb + (size_t)(cg * CPG) * HW
                                         + (size_t)y0 * W + x0;
                    int c = cg * CPG;
                    for (int ci = 0; ci < CPG; ++ci, ++c) {
                        const float v00 = pr[0], v01 = pr[1];
                        const float v10 = pr[W], v11 = pr[W + 1];
                        const float top = v00 + wx * (v01 - v00);
                        const float bot = v10 + wx * (v11 - v10);
                        const float acc = top + wy * (bot - top);
                        dst[(c * P + p) ^ swz] = f2bf(acc * mk);
                        pr += HW;
                    }
                } else {
                    const bool y0ok = (y0 >= 0 && y0 < H);
                    const bool y1ok = (y0 + 1 >= 0 && y0 + 1 < H);
                    const bool x0ok = (x0 >= 0 && x0 < W);
                    const bool x1ok = (x0 + 1 >= 0 && x0 + 1 < W);
                    const float w00 = (1.0f - wy) * (1.0f - wx);
                    const float w01 = (1.0f - wy) * wx;
                    const float w10 = wy * (1.0f - wx);
                    const float w11 = wy * wx;
                    const float* xc = xb + (size_t)(cg * CPG) * HW;
                    int c = cg * CPG;
                    for (int ci = 0; ci < CPG; ++ci, ++c) {
                        float acc = 0.0f;
                        if (y0ok) {
                            const float* pr = xc + (size_t)y0 * W + x0;
                            if (x0ok) acc += pr[0] * w00;
                            if (x1ok) acc += pr[1] * w01;
                        }
                        if (y1ok) {
                            const float* pr = xc + (size_t)(y0 + 1) * W + x0;
                            if (x0ok) acc += pr[0] * w10;
                            if (x1ok) acc += pr[1] * w11;
                        }
                        dst[(c * P + p) ^ swz] = f2bf(acc * mk);
                        xc += HW;
                    }
                }
            }
        }
        // zero-fill padded K region
        if constexpr (Rpad != R) {
            for (int idx = tid; idx < (Rpad - R) * TILE; idx += 256) {
                const int r   = R + idx / TILE;
                const int pix = idx % TILE;
                s_u[pix * Rpad + (r ^ ((pix & 7) << 3))] = 0;
            }
        }
    }
    __syncthreads();

    // ---- phase 3: main conv via MFMA ----
    {
        f32x4 acc3[MT3PW][NT] = {};
        for (int kt = 0; kt < KT; ++kt) {
            bfrag8 bfr[NT];
            #pragma unroll
            for (int nt = 0; nt < NT; ++nt)
                bfr[nt] = *(const bfrag8*)&s_u[(nt * 16 + lr) * Rpad +
                              ((kt * 32 + lk8) ^ ((lr & 7) << 3))];
            #pragma unroll
            for (int i = 0; i < MT3PW; ++i) {
                const int mt = wid + 4 * i;
                if (mt < MT3) {
                    const bfrag8 afr = *(const bfrag8*)&wpk[
                        (size_t)(mt * 16 + lr) * Rpad + kt * 32 + lk8];
                    #pragma unroll
                    for (int nt = 0; nt < NT; ++nt)
                        acc3[i][nt] = __builtin_amdgcn_mfma_f32_16x16x32_bf16(
                            afr, bfr[nt], acc3[i][nt], 0, 0, 0);
                }
            }
        }
        if (lr < LRLIM) {
            #pragma unroll
            for (int i = 0; i < MT3PW; ++i) {
                const int mt = wid + 4 * i;
                if (mt < MT3) {
                    #pragma unroll
                    for (int nt = 0; nt < NT; ++nt) {
                        #pragma unroll
                        for (int q = 0; q < 4; ++q) {
                            const int ch = mt * 16 + (lane >> 4) * 4 + q;
                            out[(((size_t)b * COUT + ch) * Ho + oy0) * Wo
                                + ox0 + nt * 16 + lr] = acc3[i][nt][q] + bias[ch];
                        }
                    }
                }
            }
        }
    }
}

// ================= instance norm (one block per (b,c) plane) =================
// float4-vectorized; BS templated (1024 thr for large planes).
template<int BS>
__global__ __launch_bounds__(BS) void in_relu_kernel(float* __restrict__ data,
                                                     int HW, int relu)
{
    float* plane = data + (size_t)blockIdx.x * HW;
    const int tid = threadIdx.x;
    float s = 0.0f, s2 = 0.0f;
    for (int i = tid * 4; i < HW; i += BS * 4) {
        const float4 v = *(const float4*)&plane[i];
        s  += v.x + v.y + v.z + v.w;
        s2 += v.x * v.x + v.y * v.y + v.z * v.z + v.w * v.w;
    }
    __shared__ float red0[BS];
    __shared__ float red1[BS];
    red0[tid] = s; red1[tid] = s2;
    __syncthreads();
    for (int off = BS / 2; off > 0; off >>= 1) {
        if (tid < off) { red0[tid] += red0[tid + off]; red1[tid] += red1[tid + off]; }
        __syncthreads();
    }
    const float mean = red0[0] / (float)HW;
    float var = red1[0] / (float)HW - mean * mean;
    var = fmaxf(var, 0.0f);
    const float rstd = rsqrtf(var + EPS);
    for (int i = tid * 4; i < HW; i += BS * 4) {
        float4 v = *(const float4*)&plane[i];
        v.x = (v.x - mean) * rstd; v.y = (v.y - mean) * rstd;
        v.z = (v.z - mean) * rstd; v.w = (v.w - mean) * rstd;
        if (relu) {
            v.x = fmaxf(v.x, 0.0f); v.y = fmaxf(v.y, 0.0f);
            v.z = fmaxf(v.z, 0.0f); v.w = fmaxf(v.w, 0.0f);
        }
        *(float4*)&plane[i] = v;
    }
}

// h += 0.1 * instance_norm(r)   (in-place on workspace h)
__global__ __launch_bounds__(256) void in_resadd_kernel(float* __restrict__ h,
                                                        const float* __restrict__ r,
                                                        int HW)
{
    const float* plane = r + (size_t)blockIdx.x * HW;
    float* hp = h + (size_t)blockIdx.x * HW;
    const int tid = threadIdx.x;
    float s = 0.0f, s2 = 0.0f;
    for (int i = tid * 4; i < HW; i += 1024) {
        const float4 v = *(const float4*)&plane[i];
        s  += v.x + v.y + v.z + v.w;
        s2 += v.x * v.x + v.y * v.y + v.z * v.z + v.w * v.w;
    }
    __shared__ float red0[256];
    __shared__ float red1[256];
    red0[tid] = s; red1[tid] = s2;
    __syncthreads();
    for (int off = 128; off > 0; off >>= 1) {
        if (tid < off) { red0[tid] += red0[tid + off]; red1[tid] += red1[tid + off]; }
        __syncthreads();
    }
    const float mean = red0[0] / (float)HW;
    float var = red1[0] / (float)HW - mean * mean;
    var = fmaxf(var, 0.0f);
    const float rstd = rsqrtf(var + EPS);
    for (int i = tid * 4; i < HW; i += 1024) {
        const float4 v = *(const float4*)&plane[i];
        float4 o = *(const float4*)&hp[i];
        o.x += 0.1f * ((v.x - mean) * rstd);
        o.y += 0.1f * ((v.y - mean) * rstd);
        o.z += 0.1f * ((v.z - mean) * rstd);
        o.w += 0.1f * ((v.w - mean) * rstd);
        *(float4*)&hp[i] = o;
    }
}

// dst = h + 0.1 * instance_norm(r)   (d_out written exactly once at the end)
__global__ __launch_bounds__(256) void in_resadd_out_kernel(
    float* __restrict__ dst, const float* __restrict__ h,
    const float* __restrict__ r, int HW)
{
    const float* plane = r + (size_t)blockIdx.x * HW;
    const float* hp = h + (size_t)blockIdx.x * HW;
    float* dp = dst + (size_t)blockIdx.x * HW;
    const int tid = threadIdx.x;
    float s = 0.0f, s2 = 0.0f;
    for (int i = tid * 4; i < HW; i += 1024) {
        const float4 v = *(const float4*)&plane[i];
        s  += v.x + v.y + v.z + v.w;
        s2 += v.x * v.x + v.y * v.y + v.z * v.z + v.w * v.w;
    }
    __shared__ float red0[256];
    __shared__ float red1[256];
    red0[tid] = s; red1[tid] = s2;
    __syncthreads();
    for (int off = 128; off > 0; off >>= 1) {
        if (tid < off) { red0[tid] += red0[tid + off]; red1[tid] += red1[tid + off]; }
        __syncthreads();
    }
    const float mean = red0[0] / (float)HW;
    float var = red1[0] / (float)HW - mean * mean;
    var = fmaxf(var, 0.0f);
    const float rstd = rsqrtf(var + EPS);
    for (int i = tid * 4; i < HW; i += 1024) {
        const float4 v = *(const float4*)&plane[i];
        const float4 o = *(const float4*)&hp[i];
        float4 d;
        d.x = o.x + 0.1f * ((v.x - mean) * rstd);
        d.y = o.y + 0.1f * ((v.y - mean) * rstd);
        d.z = o.z + 0.1f * ((v.z - mean) * rstd);
        d.w = o.w + 0.1f * ((v.w - mean) * rstd);
        *(float4*)&dp[i] = d;
    }
}

// ================= res-conv path: tiled im2col + bf16 MFMA GEMM =============
__global__ __launch_bounds__(256) void im2col_tiled_kernel(
    const float* __restrict__ in, ushort_t* __restrict__ cols)
{
    // grid = 8 b * 32 y * 4 cgroups = 1024
    const int bid = blockIdx.x;
    const int cg = bid & 3;
    const int y  = (bid >> 2) & 31;
    const int b  = bid >> 7;
    const int c0 = cg * 64;
    const int tid = threadIdx.x;

    __shared__ float s_p[64 * 3 * 34];   // [c][row][x], 26.1 KB

    // phase A: stage input slab (zero-padded)
    for (int idx = tid; idx < 64 * 3 * 34; idx += 256) {
        const int c   = idx / 102;
        const int rem = idx % 102;
        const int r   = rem / 34;
        const int xx  = rem % 34;
        const int yy = y + r - 1;
        const int gx = xx - 1;
        float v = 0.0f;
        if (yy >= 0 && yy < 32 && gx >= 0 && gx < 32)
            v = in[(((size_t)b * 256 + c0 + c) * 32 + yy) * 32 + gx];
        s_p[idx] = v;
    }
    __syncthreads();

    // phase B: 32 xout * 16 c-quads = 512 items
    for (int it = tid; it < 512; it += 256) {
        const int xout = it >> 4;
        const int cq   = (it & 15) * 4;          // local c, multiple of 4
        const int n = b * 1024 + y * 32 + xout;
        ushort_t* oc = cols + (size_t)n * 2304 + (size_t)(c0 + cq) * 9;
        ushort_t tmp[36];
        #pragma unroll
        for (int ci = 0; ci < 4; ++ci)
            #pragma unroll
            for (int ky = 0; ky < 3; ++ky)
                #pragma unroll
                for (int kx = 0; kx < 3; ++kx)
                    tmp[ci * 9 + ky * 3 + kx] =
                        f2bf(s_p[(cq + ci) * 102 + ky * 34 + xout + kx]);
        #pragma unroll
        for (int i2 = 0; i2 < 9; ++i2) {
            unsigned long long w =
                  (unsigned long long)tmp[4 * i2]
                | ((unsigned long long)tmp[4 * i2 + 1] << 16)
                | ((unsigned long long)tmp[4 * i2 + 2] << 32)
                | ((unsigned long long)tmp[4 * i2 + 3] << 48);
            *((unsigned long long*)oc + i2) = w;   // 8B-aligned: (c0+cq)%4==0
        }
    }
}

__global__ __launch_bounds__(256) void f32_to_bf16_kernel(
    const float* __restrict__ in, ushort_t* __restrict__ out, int n)
{
    const int i = blockIdx.x * 256 + threadIdx.x;
    if (i < n) out[i] = f2bf(in[i]);
}

// C[m][n] = bias[m] + sum_k A[m][k]*Bt[n][k]; A,Bt bf16 K-contiguous.
// BM=64, BN=128, BK=64; 512 threads = 8 waves (2x4 of 32x32 each).
// Register-prefetch + DOUBLE LDS buffer: at grid 256 = 1 block/CU the
// single-buffered loop exposed ~600cy load latency per iter (no co-resident
// block to overlap). Now: issue tile t+1 loads -> MFMA tile t -> land loads
// in buf[t^1] -> ONE barrier. LDS 54 KB -> also fits 2 blocks/CU.
__global__ __launch_bounds__(512) void gemm_bf16_kernel(
    const ushort_t* __restrict__ A,   // [256][2304]
    const ushort_t* __restrict__ Bt,  // [8192][2304]
    const float* __restrict__ bias,   // [256]
    float* __restrict__ C)            // [8][256][1024], n=b*1024+pix
{
    constexpr int Kt = 2304;
    constexpr int NTILES = Kt / 64;   // 36
    __shared__ ushort_t sA[2][64][72];
    __shared__ ushort_t sB[2][128][72];

    const int m0 = blockIdx.x * 64;
    const int n0 = blockIdx.y * 128;
    const int tid  = threadIdx.x;
    const int wid  = tid >> 6, lane = tid & 63;   // wid 0..7
    const int wm = wid & 1, wn = wid >> 1;        // 2 x 4 wave grid
    const int lr = lane & 15, lk = (lane >> 4) * 8;

    const int srow = tid >> 3, sseg = (tid & 7) * 8;   // srow 0..63
    const ushort_t* ap  = A  + (size_t)(m0 + srow) * Kt + sseg;
    const ushort_t* bp0 = Bt + (size_t)(n0 + srow) * Kt + sseg;
    const ushort_t* bp1 = Bt + (size_t)(n0 + 64 + srow) * Kt + sseg;

    f32x4 acc[2][2] = {};

    // prologue: tile 0 -> buf 0
    int4 ra  = *(const int4*)(ap);
    int4 rb0 = *(const int4*)(bp0);
    int4 rb1 = *(const int4*)(bp1);
    *(int4*)&sA[0][srow][sseg]      = ra;
    *(int4*)&sB[0][srow][sseg]      = rb0;
    *(int4*)&sB[0][64 + srow][sseg] = rb1;
    __syncthreads();

    for (int t = 0; t < NTILES; ++t) {
        const int cur = t & 1;
        if (t + 1 < NTILES) {                  // issue next-tile loads early
            const int k0 = (t + 1) * 64;
            ra  = *(const int4*)(ap + k0);
            rb0 = *(const int4*)(bp0 + k0);
            rb1 = *(const int4*)(bp1 + k0);
        }
        #pragma unroll
        for (int ks = 0; ks < 2; ++ks) {       // MFMA on buf[cur]
            bfrag8 af[2], bf[2];
            #pragma unroll
            for (int mi = 0; mi < 2; ++mi)
                af[mi] = *(const bfrag8*)&sA[cur][wm * 32 + mi * 16 + lr][ks * 32 + lk];
            #pragma unroll
            for (int nj = 0; nj < 2; ++nj)
                bf[nj] = *(const bfrag8*)&sB[cur][wn * 32 + nj * 16 + lr][ks * 32 + lk];
            #pragma unroll
            for (int mi = 0; mi < 2; ++mi)
                #pragma unroll
                for (int nj = 0; nj < 2; ++nj)
                    acc[mi][nj] = __builtin_amdgcn_mfma_f32_16x16x32_bf16(
                        af[mi], bf[nj], acc[mi][nj], 0, 0, 0);
        }
        if (t + 1 < NTILES) {                  // land loads in buf[cur^1]
            *(int4*)&sA[cur ^ 1][srow][sseg]      = ra;
            *(int4*)&sB[cur ^ 1][srow][sseg]      = rb0;
            *(int4*)&sB[cur ^ 1][64 + srow][sseg] = rb1;
        }
        __syncthreads();                       // buf[cur^1] visible for t+1
    }

    #pragma unroll
    for (int mi = 0; mi < 2; ++mi) {
        #pragma unroll
        for (int nj = 0; nj < 2; ++nj) {
            const int n = n0 + wn * 32 + nj * 16 + lr;
            const int b = n >> 10, pix = n & 1023;
            #pragma unroll
            for (int r = 0; r < 4; ++r) {
                const int m = m0 + wm * 32 + mi * 16 + (lane >> 4) * 4 + r;
                C[(((size_t)b * 256 + m) << 10) + pix] = acc[mi][nj][r] + bias[m];
            }
        }
    }
}

// ================= launch =================
extern "C" void kernel_launch(void* const* d_in, const int* in_sizes, int n_in,
                              void* d_out, int out_size, void* d_ws, size_t ws_size,
                              hipStream_t stream)
{
    const float* x    = (const float*)d_in[0];
    const float* d1w  = (const float*)d_in[1];
    const float* d1b  = (const float*)d_in[2];
    const float* d1ow = (const float*)d_in[3];
    const float* d1ob = (const float*)d_in[4];
    const float* d2w  = (const float*)d_in[5];
    const float* d2b  = (const float*)d_in[6];
    const float* d2ow = (const float*)d_in[7];
    const float* d2ob = (const float*)d_in[8];
    const float* d3w  = (const float*)d_in[9];
    const float* d3b  = (const float*)d_in[10];
    const float* d3ow = (const float*)d_in[11];
    const float* d3ob = (const float*)d_in[12];
    const float* d4w  = (const float*)d_in[13];
    const float* d4b  = (const float*)d_in[14];
    const float* d4ow = (const float*)d_in[15];
    const float* d4ob = (const float*)d_in[16];
    const float* resw = (const float*)d_in[17];
    const float* resb = (const float*)d_in[18];

    float* A   = (float*)d_ws;          // [0 .. 16,777,216) floats
    float* Bb  = A + 16777216;          // [16,777,216 .. 25,165,824) floats
    float* out = (float*)d_out;         // 8x256x32x32, write-once at the end

    // dcn weight packs live in d_out's bytes (free scratch: d_out is fully
    // overwritten by the final kernel). 897,024 ushorts = 1.79 MB < 8.4 MB.
    ushort_t* pk = (ushort_t*)d_out;
    ushort_t* ow1 = pk;                 // 160*192
    ushort_t* w1  = ow1 + 160 * 192;    // 32*192
    ushort_t* ow2 = w1  + 32 * 192;     // 48*512
    ushort_t* w2  = ow2 + 48 * 512;     // 64*512
    ushort_t* ow3 = w2  + 64 * 512;     // 48*1024
    ushort_t* w3  = ow3 + 48 * 1024;    // 128*1024
    ushort_t* ow4 = w3  + 128 * 1024;   // 48*2048
    ushort_t* w4  = ow4 + 48 * 2048;    // 256*2048

    // workspace sub-regions for the res phase:
    float* r    = A;                                   // [0 .. 2,097,152)
    float* r2   = A + 2097152;
    ushort_t* cols = (ushort_t*)(A + 4194304);         // 8192*2304 bf16
    ushort_t* wbf  = (ushort_t*)Bb;                    // 4*589,824 bf16
    float* H4   = Bb + 4194304;                        // 2,097,152 floats

    const int B = 8;

    // ---- weight prepack (bf16, K-padded) ----
    pack_w_kernel<<<(160 * 192 + 255) / 256, 256, 0, stream>>>(d1ow, ow1, 147, 147, 160, 192);
    pack_w_kernel<<<(32 * 192 + 255) / 256, 256, 0, stream>>>(d1w, w1, 32, 147, 32, 192);
    pack_w_kernel<<<(48 * 512 + 255) / 256, 256, 0, stream>>>(d2ow, ow2, 48, 512, 48, 512);
    pack_w_kernel<<<(64 * 512 + 255) / 256, 256, 0, stream>>>(d2w, w2, 64, 512, 64, 512);
    pack_w_kernel<<<(48 * 1024 + 255) / 256, 256, 0, stream>>>(d3ow, ow3, 48, 1024, 48, 1024);
    pack_w_kernel<<<(128 * 1024 + 255) / 256, 256, 0, stream>>>(d3w, w3, 128, 1024, 128, 1024);
    pack_w_kernel<<<(48 * 2048 + 255) / 256, 256, 0, stream>>>(d4ow, ow4, 48, 2048, 48, 2048);
    pack_w_kernel<<<(256 * 2048 + 255) / 256, 256, 0, stream>>>(d4w, w4, 256, 2048, 256, 2048);

    // dcn1: 3->32, K=7 s=1 p=3; 256x256  (NT=2, fp32 halo patch + bf16 mask)
    dcn_mfma_kernel<3, 32, 7, 1, 3, 32, 2><<<B * (256 * 256 / 32), 256, 0, stream>>>(
        x, 256, 256, w1, d1b, ow1, d1ob, A, 256, 256);
    in_relu_kernel<1024><<<B * 32, 1024, 0, stream>>>(A, 65536, 1);

    // dcn2: 32->64, K=4 s=2 p=1; 256 -> 128  (bf16 halo patch; ~32.8 KB)
    dcn_mfma_kernel<32, 64, 4, 2, 1, 16, 3><<<B * (128 * 128 / 16), 256, 0, stream>>>(
        A, 256, 256, w2, d2b, ow2, d2ob, Bb, 128, 128);
    in_relu_kernel<1024><<<B * 64, 1024, 0, stream>>>(Bb, 16384, 1);

    // dcn3: 64->128, K=4 s=2 p=1; 128 -> 64  (bf16 halo patch, TILE=8; ~33 KB)
    dcn_mfma_kernel<64, 128, 4, 2, 1, 8, 3><<<B * (64 * 64 / 8), 256, 0, stream>>>(
        Bb, 128, 128, w3, d3b, ow3, d3ob, A, 64, 64);
    in_relu_kernel<1024><<<B * 128, 1024, 0, stream>>>(A, 4096, 1);

    // dcn4: 128->256, K=4 s=2 p=1; 64 -> 32 -> H4  (patchless TILE=8; ~34 KB)
    dcn_mfma_kernel<128, 256, 4, 2, 1, 8, 0><<<B * (32 * 32 / 8), 256, 0, stream>>>(
        A, 64, 64, w4, d4b, ow4, d4ob, H4, 32, 32);
    in_relu_kernel<256><<<B * 256, 256, 0, stream>>>(H4, 1024, 1);

    // --- residual blocks via bf16 MFMA GEMM ---
    f32_to_bf16_kernel<<<(4 * 589824 + 255) / 256, 256, 0, stream>>>(
        resw, wbf, 4 * 589824);

    dim3 ggrid(4, 64);
    // i = 0 : h (H4) updated in place
    im2col_tiled_kernel<<<1024, 256, 0, stream>>>(H4, cols);
    gemm_bf16_kernel<<<ggrid, 512, 0, stream>>>(
        wbf + (size_t)0 * 589824, cols, resb + 0 * 256, r);
    in_relu_kernel<256><<<B * 256, 256, 0, stream>>>(r, 1024, 1);
    im2col_tiled_kernel<<<1024, 256, 0, stream>>>(r, cols);
    gemm_bf16_kernel<<<ggrid, 512, 0, stream>>>(
        wbf + (size_t)1 * 589824, cols, resb + 1 * 256, r2);
    in_resadd_kernel<<<B * 256, 256, 0, stream>>>(H4, r2, 1024);

    // i = 1 : final result goes straight to d_out (write-once, covers packs)
    im2col_tiled_kernel<<<1024, 256, 0, stream>>>(H4, cols);
    gemm_bf16_kernel<<<ggrid, 512, 0, stream>>>(
        wbf + (size_t)2 * 589824, cols, resb + 2 * 256, r);
    in_relu_kernel<256><<<B * 256, 256, 0, stream>>>(r, 1024, 1);
    im2col_tiled_kernel<<<1024, 256, 0, stream>>>(r, cols);
    gemm_bf16_kernel<<<ggrid, 512, 0, stream>>>(
        wbf + (size_t)3 * 589824, cols, resb + 3 * 256, r2);
    in_resadd_out_kernel<<<B * 256, 256, 0, stream>>>(out, H4, r2, 1024);
}